// Round 5
// baseline (612.251 us; speedup 1.0000x reference)
//
#include <hip/hip_runtime.h>
#include <hip/hip_bf16.h>
#include <math.h>

#define NEG_SLOPE 0.2f

// ---------------- utility ----------------
__global__ void zero_i32(int* __restrict__ p, int n) {
    int i = blockIdx.x * blockDim.x + threadIdx.x;
    if (i < n) p[i] = 0;
}

// ---------------- CSR build (both branches in one dispatch) ----------------
__global__ void count_edges2(const int* __restrict__ dst0, const int* __restrict__ dst1,
                             int* __restrict__ cnt, int N, int E) {
    int i = blockIdx.x * blockDim.x + threadIdx.x;
    if (i >= 2 * E) return;
    int br = i >= E;
    int j = i - br * E;
    const int* d = br ? dst1 : dst0;
    atomicAdd(&cnt[br * N + d[j]], 1);
}

// scan + zero cnt in place (cnt reused as fill[] by scatter afterwards)
__global__ void scan_block(int* __restrict__ cnt_all, int* __restrict__ rs_all, int N) {
    __shared__ int s[1024];
    int br = blockIdx.x;
    int* cnt = cnt_all + br * N;
    int* rs = rs_all + br * (N + 1);
    int tid = threadIdx.x;
    int running = 0;
    for (int base = 0; base < N; base += 1024) {
        int v = (base + tid < N) ? cnt[base + tid] : 0;
        if (base + tid < N) cnt[base + tid] = 0;
        __syncthreads();
        s[tid] = v;
        __syncthreads();
        for (int off = 1; off < 1024; off <<= 1) {
            int t = (tid >= off) ? s[tid - off] : 0;
            __syncthreads();
            if (tid >= off) s[tid] += t;
            __syncthreads();
        }
        if (base + tid < N) rs[base + tid] = running + s[tid] - v;
        running += s[1023];
    }
    if (tid == 0) rs[N] = running;
}

__global__ void scatter_edges2(const int* __restrict__ dst0, const int* __restrict__ dst1,
                               const int* __restrict__ rs_all, int* __restrict__ fill_all,
                               int* __restrict__ eidx_all, int N, int E) {
    int i = blockIdx.x * blockDim.x + threadIdx.x;
    if (i >= 2 * E) return;
    int br = i >= E;
    int j = i - br * E;
    const int* d = br ? dst1 : dst0;
    int dd = d[j];
    int pos = atomicAdd(&fill_all[br * N + dd], 1);
    eidx_all[br * E + rs_all[br * (N + 1) + dd] + pos] = j;
}

// ---------------- bf16 hi/lo helpers ----------------
__device__ __forceinline__ short f2bf(float x) {
    __hip_bfloat16 h = __float2bfloat16(x);
    return *reinterpret_cast<short*>(&h);
}
__device__ __forceinline__ float bf2f(short s) {
    unsigned int u = ((unsigned int)(unsigned short)s) << 16;
    return __uint_as_float(u);
}
__device__ __forceinline__ float us2f(unsigned short s) {
    return __uint_as_float((unsigned int)s << 16);
}

// ---------------- merged weight prep + feat hi/lo split ---------------------
__device__ __forceinline__ void split_w_elem(const float* W, short* W2t, int K, int N, int idx) {
    int k = idx / N, n = idx - k * N;
    float x = W[idx];
    short hs = f2bf(x);
    short ls = f2bf(x - bf2f(hs));
    size_t base = (size_t)n * 2 * K;
    W2t[base + k] = hs;
    W2t[base + K + k] = ls;
}
__device__ __forceinline__ void split_cw_elem(const float* w, short* w2, int Kp, int idx) {
    int o = idx / Kp, k = idx - o * Kp;
    float x = w[idx];
    short hs = f2bf(x);
    short ls = f2bf(x - bf2f(hs));
    size_t base = (size_t)o * 2 * Kp;
    w2[base + k] = hs;
    w2[base + Kp + k] = ls;
}
__global__ void prep_weights(const float* __restrict__ Wg1, const float* __restrict__ Wg2,
                             const float* __restrict__ Wg3, const float* __restrict__ c1w,
                             const float* __restrict__ c2w, const float* __restrict__ c3w,
                             short* __restrict__ w2t1, short* __restrict__ w2t2,
                             short* __restrict__ w2t3, short* __restrict__ cw1,
                             short* __restrict__ cw2, short* __restrict__ cw3,
                             const float* __restrict__ feat0, const float* __restrict__ feat1,
                             short* __restrict__ fsplit) {
    int idx = blockIdx.x * blockDim.x + threadIdx.x;
    if (idx < 12288)       split_w_elem(Wg1, w2t1, 64, 192, idx);
    else if (idx < 122880) split_w_elem(Wg2, w2t2, 192, 576, idx - 12288);
    else if (idx < 454656) split_w_elem(Wg3, w2t3, 576, 576, idx - 122880);
    else if (idx < 479232) split_cw_elem(c1w, cw1, 192, idx - 454656);
    else if (idx < 528384) split_cw_elem(c2w, cw2, 384, idx - 479232);
    else if (idx < 577536) split_cw_elem(c3w, cw3, 384, idx - 528384);
    else if (idx < 1601536) {
        int j = idx - 577536;           // 0..1023999 = 2 x 8000 x 64
        int br = j >= 512000;
        int e = j - br * 512000;        // n*64 + k
        int n = e >> 6, k = e & 63;
        float x = (br ? feat1 : feat0)[e];
        short hs = f2bf(x);
        short ls = f2bf(x - bf2f(hs));
        short* fs = fsplit + (size_t)br * 1024000;  // 8000 * 128
        fs[n * 128 + k] = hs;
        fs[n * 128 + 64 + k] = ls;
    }
}

// ---------------- MFMA bf16-split GEMM v5 ----------------------------------
// A pre-split hi/lo ([row][2K]: hi K then lo K), XOR-swizzled unpadded LDS
// (rows = 8 x 16B slots, slot ^= row&7), 32-row M-tiles for occupancy.
typedef __attribute__((ext_vector_type(8))) short short8;
typedef __attribute__((ext_vector_type(4))) short short4v;
typedef __attribute__((ext_vector_type(4))) float floatx4;

__global__ __launch_bounds__(256) void gemm_split(const short* __restrict__ Abase,
                                                  const short* __restrict__ Bt,
                                                  unsigned short* __restrict__ Cbf,
                                                  int M, int K, int N,
                                                  size_t aBrStride, size_t cBrStride) {
    __shared__ __align__(16) short sA[32 * 64];
    __shared__ __align__(16) short sB[192 * 64];
    int tid = threadIdx.x;
    int wave = tid >> 6, lane = tid & 63;
    int m = lane & 15, q = lane >> 4;
    int row0 = blockIdx.y << 5;
    int col0 = blockIdx.x * 192;
    const short* A = Abase + blockIdx.z * aBrStride;
    unsigned short* Cbfb = Cbf + blockIdx.z * cBrStride;
    int K2 = K * 2;
    floatx4 acc[2][3];
#pragma unroll
    for (int rt = 0; rt < 2; ++rt)
#pragma unroll
        for (int ct = 0; ct < 3; ++ct) acc[rt][ct] = (floatx4){0.f, 0.f, 0.f, 0.f};

    // per-thread staging addresses (k0-invariant parts)
    int ar = tid >> 3, asl = tid & 7;
    const short* aSrc = A + (size_t)(row0 + ar) * K2 +
                        (asl < 4 ? (asl << 3) : (K + ((asl - 4) << 3)));
    int aDst = (ar << 6) + ((asl ^ (ar & 7)) << 3);
    const short* bSrc[6];
    int bDst[6];
#pragma unroll
    for (int p = 0; p < 6; ++p) {
        int t = tid + (p << 8);
        int n = t >> 3, sl = t & 7;
        bSrc[p] = Bt + (size_t)(col0 + n) * K2 +
                  (sl < 4 ? (sl << 3) : (K + ((sl - 4) << 3)));
        bDst[p] = (n << 6) + ((sl ^ (n & 7)) << 3);
    }
    int sw_hi = (q ^ (m & 7)) << 3;
    int sw_lo = ((4 + q) ^ (m & 7)) << 3;

    for (int k0 = 0; k0 < K; k0 += 32) {
        *(short8*)&sA[aDst] = *(const short8*)(aSrc + k0);
#pragma unroll
        for (int p = 0; p < 6; ++p)
            *(short8*)&sB[bDst[p]] = *(const short8*)(bSrc[p] + k0);
        __syncthreads();
        short8 a_hi[2], a_lo[2];
#pragma unroll
        for (int rt = 0; rt < 2; ++rt) {
            int row = rt * 16 + m;
            a_hi[rt] = *(const short8*)&sA[(row << 6) + sw_hi];
            a_lo[rt] = *(const short8*)&sA[(row << 6) + sw_lo];
        }
#pragma unroll
        for (int ct = 0; ct < 3; ++ct) {
            int bn = wave * 48 + ct * 16 + m;
            short8 b_hi = *(const short8*)&sB[(bn << 6) + sw_hi];
            short8 b_lo = *(const short8*)&sB[(bn << 6) + sw_lo];
#pragma unroll
            for (int rt = 0; rt < 2; ++rt) {
                acc[rt][ct] = __builtin_amdgcn_mfma_f32_16x16x32_bf16(a_hi[rt], b_hi, acc[rt][ct], 0, 0, 0);
                acc[rt][ct] = __builtin_amdgcn_mfma_f32_16x16x32_bf16(a_lo[rt], b_hi, acc[rt][ct], 0, 0, 0);
                acc[rt][ct] = __builtin_amdgcn_mfma_f32_16x16x32_bf16(a_hi[rt], b_lo, acc[rt][ct], 0, 0, 0);
            }
        }
        __syncthreads();
    }
#pragma unroll
    for (int rt = 0; rt < 2; ++rt)
#pragma unroll
        for (int ct = 0; ct < 3; ++ct)
#pragma unroll
            for (int r = 0; r < 4; ++r) {
                size_t idx = (size_t)(row0 + rt * 16 + q * 4 + r) * N + col0 + wave * 48 + ct * 16 + m;
                Cbfb[idx] = (unsigned short)f2bf(acc[rt][ct][r]);
            }
    (void)M;
}

// ---------------- GAT pieces (branch-fused; h in bf16) ----------------
__global__ void gat_elr(const unsigned short* __restrict__ h, const float* __restrict__ al,
                        const float* __restrict__ ar, float* __restrict__ el,
                        float* __restrict__ er, int N, int H, int D,
                        size_t hBr, size_t eBr) {
    int wid = (blockIdx.x * blockDim.x + threadIdx.x) >> 6;
    int lane = threadIdx.x & 63;
    if (wid >= 2 * N * H) return;
    int br = wid / (N * H);
    int loc = wid - br * N * H;
    int n = loc / H, hh = loc - n * H;
    const unsigned short* hp = h + br * hBr + ((size_t)n * H + hh) * D;
    const float* alp = al + (size_t)hh * D;
    const float* arp = ar + (size_t)hh * D;
    float sl = 0.f, sr = 0.f;
    for (int d = lane; d < D; d += 64) {
        float v = us2f(hp[d]);
        sl += v * alp[d];
        sr += v * arp[d];
    }
    for (int off = 32; off > 0; off >>= 1) {
        sl += __shfl_down(sl, off, 64);
        sr += __shfl_down(sr, off, 64);
    }
    if (lane == 0) { el[br * eBr + loc] = sl; er[br * eBr + loc] = sr; }
}

__device__ __forceinline__ float lrelu(float v) {
    return (v > 0.f) ? v : NEG_SLOPE * v;
}

// ---------------- per-node softmax -> per-edge records {src, a0,a1,a2} ------
__global__ __launch_bounds__(128) void gat_alpha(
        const float* __restrict__ el_all, const float* __restrict__ er_all,
        const int* __restrict__ src0, const int* __restrict__ src1,
        const int* __restrict__ rs_all, const int* __restrict__ eidx_all,
        float4* __restrict__ rec_all, int N, int H, int E, size_t eBr) {
    int n = blockIdx.x * 2 + (threadIdx.x >> 6);
    int br = blockIdx.y;
    if (n >= N) return;
    const int* src = br ? src1 : src0;
    const int* rs = rs_all + br * (N + 1);
    const int* eidx = eidx_all + br * E;
    const float* el = el_all + br * eBr;
    const float* er = er_all + br * eBr;
    float4* rec = rec_all + (size_t)br * E;
    int lane = threadIdx.x & 63;
    int s0 = rs[n], s1 = rs[n + 1];
    int deg = s1 - s0;
    if (deg <= 0) return;
    float ern0 = er[n * H + 0];
    float ern1 = (H > 1) ? er[n * H + 1] : 0.f;
    float ern2 = (H > 2) ? er[n * H + 2] : 0.f;
    if (deg <= 64) {
        int s = 0;
        float v0 = -INFINITY, v1 = -INFINITY, v2 = -INFINITY;
        if (lane < deg) {
            int e = eidx[s0 + lane];
            s = src[e];
            v0 = lrelu(el[s * H + 0] + ern0);
            if (H > 1) {
                v1 = lrelu(el[s * H + 1] + ern1);
                v2 = lrelu(el[s * H + 2] + ern2);
            }
        }
        float m0 = v0, m1 = v1, m2 = v2;
#pragma unroll
        for (int off = 32; off > 0; off >>= 1) {
            m0 = fmaxf(m0, __shfl_xor(m0, off, 64));
            m1 = fmaxf(m1, __shfl_xor(m1, off, 64));
            m2 = fmaxf(m2, __shfl_xor(m2, off, 64));
        }
        float ex0 = (lane < deg) ? expf(v0 - m0) : 0.f;
        float ex1 = (lane < deg && H > 1) ? expf(v1 - m1) : 0.f;
        float ex2 = (lane < deg && H > 2) ? expf(v2 - m2) : 0.f;
        float d0 = ex0, d1 = ex1, d2 = ex2;
#pragma unroll
        for (int off = 32; off > 0; off >>= 1) {
            d0 += __shfl_xor(d0, off, 64);
            d1 += __shfl_xor(d1, off, 64);
            d2 += __shfl_xor(d2, off, 64);
        }
        if (lane < deg) {
            float4 r;
            r.x = __int_as_float(s);
            r.y = ex0 / d0;
            r.z = (H > 1) ? ex1 / d1 : 0.f;
            r.w = (H > 2) ? ex2 / d2 : 0.f;
            rec[s0 + lane] = r;
        }
    } else {
        float m0 = -INFINITY, m1 = -INFINITY, m2 = -INFINITY;
        for (int j = s0 + lane; j < s1; j += 64) {
            int e = eidx[j], s = src[e];
            m0 = fmaxf(m0, lrelu(el[s * H + 0] + ern0));
            if (H > 1) {
                m1 = fmaxf(m1, lrelu(el[s * H + 1] + ern1));
                m2 = fmaxf(m2, lrelu(el[s * H + 2] + ern2));
            }
        }
#pragma unroll
        for (int off = 32; off > 0; off >>= 1) {
            m0 = fmaxf(m0, __shfl_xor(m0, off, 64));
            m1 = fmaxf(m1, __shfl_xor(m1, off, 64));
            m2 = fmaxf(m2, __shfl_xor(m2, off, 64));
        }
        float d0 = 0.f, d1 = 0.f, d2 = 0.f;
        for (int j = s0 + lane; j < s1; j += 64) {
            int e = eidx[j], s = src[e];
            d0 += expf(lrelu(el[s * H + 0] + ern0) - m0);
            if (H > 1) {
                d1 += expf(lrelu(el[s * H + 1] + ern1) - m1);
                d2 += expf(lrelu(el[s * H + 2] + ern2) - m2);
            }
        }
#pragma unroll
        for (int off = 32; off > 0; off >>= 1) {
            d0 += __shfl_xor(d0, off, 64);
            d1 += __shfl_xor(d1, off, 64);
            d2 += __shfl_xor(d2, off, 64);
        }
        float i0 = 1.f / d0;
        float i1 = (H > 1) ? 1.f / d1 : 0.f;
        float i2 = (H > 2) ? 1.f / d2 : 0.f;
        for (int j = s0 + lane; j < s1; j += 64) {
            int e = eidx[j], s = src[e];
            float4 r;
            r.x = __int_as_float(s);
            r.y = expf(lrelu(el[s * H + 0] + ern0) - m0) * i0;
            r.z = (H > 1) ? expf(lrelu(el[s * H + 1] + ern1) - m1) * i1 : 0.f;
            r.w = (H > 2) ? expf(lrelu(el[s * H + 2] + ern2) - m2) * i2 : 0.f;
            rec[j] = r;
        }
    }
}

// ---------------- full-row aggregation from precomputed records -------------
// splitOut=1: write hi/lo bf16 planes ([n][2HD]: hi HD then lo HD) for the
// next layer's GEMM A operand. splitOut=0: write f32 (layer 3 -> seg_max).
__global__ __launch_bounds__(192) void gat_agg(
        const unsigned short* __restrict__ hb_all, const float4* __restrict__ rec_all,
        const int* __restrict__ rs_all, float4* __restrict__ out4_all,
        short* __restrict__ osplit_all,
        int N, int H, int D, int E, size_t hBr, size_t o4Br, size_t osBr, int splitOut) {
    int n = blockIdx.x;
    int br = blockIdx.y;
    int HD = H * D;
    int HD4 = HD >> 2;
    int tid = threadIdx.x;
    if (tid >= HD4) return;
    int hh = (tid << 2) / D;
    const unsigned short* hb = hb_all + br * hBr;
    const float4* rec = rec_all + (size_t)br * E;
    const int* rs = rs_all + br * (N + 1);
    int s0 = rs[n], s1 = rs[n + 1];
    int ch = tid << 2;
    float4 a0 = {0.f, 0.f, 0.f, 0.f};
    float4 a1 = {0.f, 0.f, 0.f, 0.f};
    float4 a2 = {0.f, 0.f, 0.f, 0.f};
    float4 a3 = {0.f, 0.f, 0.f, 0.f};
    int i = s0;
    for (; i + 3 < s1; i += 4) {
        float4 r0 = rec[i];
        float4 r1 = rec[i + 1];
        float4 r2 = rec[i + 2];
        float4 r3 = rec[i + 3];
        int sA = __float_as_int(r0.x);
        int sB = __float_as_int(r1.x);
        int sC = __float_as_int(r2.x);
        int sD = __float_as_int(r3.x);
        ushort4 h0 = *(const ushort4*)&hb[(size_t)sA * HD + ch];
        ushort4 h1 = *(const ushort4*)&hb[(size_t)sB * HD + ch];
        ushort4 h2 = *(const ushort4*)&hb[(size_t)sC * HD + ch];
        ushort4 h3 = *(const ushort4*)&hb[(size_t)sD * HD + ch];
        float w0 = (hh == 0) ? r0.y : ((hh == 1) ? r0.z : r0.w);
        float w1 = (hh == 0) ? r1.y : ((hh == 1) ? r1.z : r1.w);
        float w2 = (hh == 0) ? r2.y : ((hh == 1) ? r2.z : r2.w);
        float w3 = (hh == 0) ? r3.y : ((hh == 1) ? r3.z : r3.w);
        a0.x += w0 * us2f(h0.x); a0.y += w0 * us2f(h0.y);
        a0.z += w0 * us2f(h0.z); a0.w += w0 * us2f(h0.w);
        a1.x += w1 * us2f(h1.x); a1.y += w1 * us2f(h1.y);
        a1.z += w1 * us2f(h1.z); a1.w += w1 * us2f(h1.w);
        a2.x += w2 * us2f(h2.x); a2.y += w2 * us2f(h2.y);
        a2.z += w2 * us2f(h2.z); a2.w += w2 * us2f(h2.w);
        a3.x += w3 * us2f(h3.x); a3.y += w3 * us2f(h3.y);
        a3.z += w3 * us2f(h3.z); a3.w += w3 * us2f(h3.w);
    }
    for (; i < s1; ++i) {
        float4 r0 = rec[i];
        int sA = __float_as_int(r0.x);
        ushort4 h0 = *(const ushort4*)&hb[(size_t)sA * HD + ch];
        float w0 = (hh == 0) ? r0.y : ((hh == 1) ? r0.z : r0.w);
        a0.x += w0 * us2f(h0.x); a0.y += w0 * us2f(h0.y);
        a0.z += w0 * us2f(h0.z); a0.w += w0 * us2f(h0.w);
    }
    float4 o;
    o.x = fmaxf(a0.x + a1.x + a2.x + a3.x, 0.f);
    o.y = fmaxf(a0.y + a1.y + a2.y + a3.y, 0.f);
    o.z = fmaxf(a0.z + a1.z + a2.z + a3.z, 0.f);
    o.w = fmaxf(a0.w + a1.w + a2.w + a3.w, 0.f);
    if (splitOut) {
        short* os = osplit_all + br * osBr;
        int HD2 = HD << 1;
        short4v hi, lo;
        hi[0] = f2bf(o.x); lo[0] = f2bf(o.x - bf2f(hi[0]));
        hi[1] = f2bf(o.y); lo[1] = f2bf(o.y - bf2f(hi[1]));
        hi[2] = f2bf(o.z); lo[2] = f2bf(o.z - bf2f(hi[2]));
        hi[3] = f2bf(o.w); lo[3] = f2bf(o.w - bf2f(hi[3]));
        *(short4v*)&os[(size_t)n * HD2 + ch] = hi;
        *(short4v*)&os[(size_t)n * HD2 + HD + ch] = lo;
    } else {
        out4_all[br * o4Br + (size_t)n * HD4 + tid] = o;
    }
}

// Graph max-readout (post-ReLU >=0) via int-bitcast atomicMax. grid.y = branch.
__global__ void seg_max_atomic(const float* __restrict__ g_all, const int* __restrict__ nid,
                               int* __restrict__ out_all, int N, int C,
                               size_t gBr, size_t oBr) {
    int br = blockIdx.y;
    const float* g = g_all + br * gBr;
    int* out = out_all + br * oBr;
    int n0 = blockIdx.x << 5;
    int n1 = n0 + 32; if (n1 > N) n1 = N;
    if (n0 >= N) return;
    for (int c = threadIdx.x; c < C; c += blockDim.x) {
        int cur = nid[n0];
        float m = 0.f;
        for (int n = n0; n < n1; ++n) {
            int gid = nid[n];
            if (gid != cur) {
                atomicMax(&out[cur * C + c], __float_as_int(m));
                cur = gid; m = 0.f;
            }
            m = fmaxf(m, g[(size_t)n * C + c]);
        }
        atomicMax(&out[cur * C + c], __float_as_int(m));
    }
}

// ---------------- small dense layers (grid.z = branch; strides may be 0) ----
__global__ void linear_wave(const float* __restrict__ in, const float* __restrict__ W,
                            const float* __restrict__ bias, float* __restrict__ out,
                            int K, int O, int act, size_t inBr, size_t outBr) {
    int o = blockIdx.x * 4 + (threadIdx.x >> 6);
    int b = blockIdx.y;
    int lane = threadIdx.x & 63;
    if (o >= O) return;
    const float* ip = in + blockIdx.z * inBr + (size_t)b * K;
    float acc = 0.f;
    for (int k = lane; k < K; k += 64)
        acc += ip[k] * W[(size_t)k * O + o];
    for (int off = 32; off > 0; off >>= 1)
        acc += __shfl_down(acc, off, 64);
    if (lane == 0) {
        acc += bias[o];
        if (act == 1) acc = fmaxf(acc, 0.f);
        else if (act == 2) acc = 1.f / (1.f + expf(-acc));
        out[blockIdx.z * outBr + (size_t)b * O + o] = acc;
    }
}

// fc1 fused with the branch gate (K = 256 fixed).
__global__ void linear_cat(const float* __restrict__ gvec, const float* __restrict__ sf,
                           const float* __restrict__ w1, const float* __restrict__ W,
                           const float* __restrict__ bias, float* __restrict__ out,
                           int O, int B128) {
    int o = blockIdx.x * 4 + (threadIdx.x >> 6);
    int b = blockIdx.y;
    int lane = threadIdx.x & 63;
    if (o >= 512) return;
    float w = 1.f / (1.f + expf(-w1[0]));
    float acc = 0.f;
    for (int k = lane; k < 256; k += 64) {
        int br = k >> 7, c = k & 127;
        float v = (1.f - w) * gvec[br * B128 + b * 128 + c] + w * sf[br * B128 + b * 128 + c];
        acc += v * W[(size_t)k * 512 + o];
    }
    for (int off = 32; off > 0; off >>= 1)
        acc += __shfl_down(acc, off, 64);
    if (lane == 0)
        out[(size_t)b * 512 + o] = fmaxf(acc + bias[o], 0.f);
    (void)O;
}

// ---------------- conv1d k=3 as MFMA (im2col on the fly) --------------------
__global__ __launch_bounds__(256) void conv_mfma(const float* __restrict__ x,
                                                 const float* __restrict__ x1,
                                                 const short* __restrict__ w2,
                                                 const float* __restrict__ bias,
                                                 float* __restrict__ y,
                                                 int Cin, int Lin, int Lout,
                                                 int mode, int srcLen,
                                                 size_t xBr, size_t yBr) {
    extern __shared__ __align__(16) char smem[];
    float* sx = (float*)smem;                          // Cin x 68 fp32
    short* sB = (short*)(smem + (size_t)Cin * 68 * 4); // 128 x 72 shorts
    int Kp = Cin * 3;
    int K2 = Kp * 2;
    int b = blockIdx.y;
    float* yb = y + blockIdx.z * yBr + (size_t)b * 128 * Lout;
    int l0 = blockIdx.x << 6;
    int tid = threadIdx.x;
    int wave = tid >> 6, lane = tid & 63;
    int m = lane & 15, q = lane >> 4;
    int wrow = (wave & 1) << 5;
    int wcol = (wave >> 1) << 6;
    int loadL = Lin - l0; if (loadL > 66) loadL = 66;
    if (mode == 2) {
        const float* pb = (blockIdx.z ? x1 : x) + (size_t)b * 1200 * 64;
        for (int t = tid; t < loadL * 64; t += 256) {
            int i = t >> 6, c = t & 63;
            sx[c * 68 + i] = pb[(size_t)(l0 + i) * 64 + c];
        }
    } else if (mode == 1) {
        const float* xb = x + blockIdx.z * xBr + (size_t)b * Cin * srcLen;
        for (int t = tid; t < Cin * loadL; t += 256) {
            int c = t / loadL, i = t - c * loadL;
            const float* row = &xb[(size_t)c * srcLen + 3 * (l0 + i)];
            sx[c * 68 + i] = fmaxf(fmaxf(row[0], row[1]), row[2]);
        }
    } else {
        const float* xb = x + blockIdx.z * xBr + (size_t)b * Cin * srcLen;
        for (int t = tid; t < Cin * loadL; t += 256) {
            int c = t / loadL, i = t - c * loadL;
            sx[c * 68 + i] = xb[(size_t)c * srcLen + l0 + i];
        }
    }
    floatx4 acc[2][4];
#pragma unroll
    for (int rt = 0; rt < 2; ++rt)
#pragma unroll
        for (int ct = 0; ct < 4; ++ct) acc[rt][ct] = (floatx4){0.f, 0.f, 0.f, 0.f};

    for (int k0 = 0; k0 < Kp; k0 += 32) {
#pragma unroll
        for (int p = 0; p < 4; ++p) {
            int t = tid + (p << 8);
            int o = t >> 3, slot = t & 7;
            int srcoff = k0 + ((slot & 3) << 3) + ((slot >= 4) ? Kp : 0);
            *(float4*)&sB[o * 72 + (slot << 3)] = *(const float4*)&w2[(size_t)o * K2 + srcoff];
        }
        __syncthreads();
        short8 a_hi[2], a_lo[2];
#pragma unroll
        for (int rt = 0; rt < 2; ++rt) {
            int pos = wrow + rt * 16 + m;
#pragma unroll
            for (int kk = 0; kk < 8; ++kk) {
                int k = k0 + q * 8 + kk;
                int c = k / 3, j = k - c * 3;
                float v = sx[c * 68 + pos + j];
                short hv = f2bf(v);
                a_hi[rt][kk] = hv;
                a_lo[rt][kk] = f2bf(v - bf2f(hv));
            }
        }
#pragma unroll
        for (int ct = 0; ct < 4; ++ct) {
            short8 b_hi = *(const short8*)&sB[(wcol + ct * 16 + m) * 72 + q * 8];
            short8 b_lo = *(const short8*)&sB[(wcol + ct * 16 + m) * 72 + 32 + q * 8];
#pragma unroll
            for (int rt = 0; rt < 2; ++rt) {
                acc[rt][ct] = __builtin_amdgcn_mfma_f32_16x16x32_bf16(a_hi[rt], b_hi, acc[rt][ct], 0, 0, 0);
                acc[rt][ct] = __builtin_amdgcn_mfma_f32_16x16x32_bf16(a_lo[rt], b_hi, acc[rt][ct], 0, 0, 0);
                acc[rt][ct] = __builtin_amdgcn_mfma_f32_16x16x32_bf16(a_hi[rt], b_lo, acc[rt][ct], 0, 0, 0);
            }
        }
        __syncthreads();
    }
#pragma unroll
    for (int ct = 0; ct < 4; ++ct) {
        int o = wcol + ct * 16 + m;
        float bv = bias[o];
#pragma unroll
        for (int rt = 0; rt < 2; ++rt)
#pragma unroll
            for (int r = 0; r < 4; ++r) {
                int pos = wrow + rt * 16 + q * 4 + r;
                if (l0 + pos < Lout)
                    yb[(size_t)o * Lout + l0 + pos] = acc[rt][ct][r] + bv;
            }
    }
}

// fused: global 130-max-pool over y3 + tf linear + ReLU. block per (b, br).
__global__ void pooltf(const float* __restrict__ y3, const float* __restrict__ tf_w,
                       const float* __restrict__ tf_b, float* __restrict__ sf,
                       size_t yBr, size_t sfBr) {
    __shared__ float s_sp[128];
    int b = blockIdx.x, br = blockIdx.y;
    const float* yb = y3 + br * yBr + (size_t)b * 128 * 130;
    int c = threadIdx.x;
    float mx = -INFINITY;
    for (int l = 0; l < 130; ++l) mx = fmaxf(mx, yb[(size_t)c * 130 + l]);
    s_sp[c] = mx;
    __syncthreads();
    int o = threadIdx.x;
    float acc = tf_b[o];
    for (int k = 0; k < 128; ++k) acc += s_sp[k] * tf_w[(size_t)k * 128 + o];
    sf[br * sfBr + (size_t)b * 128 + o] = fmaxf(acc, 0.f);
}

// ---------------- host ----------------
extern "C" void kernel_launch(void* const* d_in, const int* in_sizes, int n_in,
                              void* d_out, int out_size, void* d_ws, size_t ws_size,
                              hipStream_t stream) {
    const float* feat[2] = {(const float*)d_in[0], (const float*)d_in[1]};
    const float* pad[2]  = {(const float*)d_in[2], (const float*)d_in[3]};
    const int* src[2]    = {(const int*)d_in[4], (const int*)d_in[6]};
    const int* dst[2]    = {(const int*)d_in[5], (const int*)d_in[7]};
    const int* nid[2]    = {(const int*)d_in[8], (const int*)d_in[9]};
    const float* Wg[3]   = {(const float*)d_in[11], (const float*)d_in[14], (const float*)d_in[17]};
    const float* al[3]   = {(const float*)d_in[12], (const float*)d_in[15], (const float*)d_in[18]};
    const float* ar[3]   = {(const float*)d_in[13], (const float*)d_in[16], (const float*)d_in[19]};
    const float* fcg_w = (const float*)d_in[20]; const float* fcg_b = (const float*)d_in[21];
    const float* c1w = (const float*)d_in[22];   const float* c1b = (const float*)d_in[23];
    const float* c2w = (const float*)d_in[24];   const float* c2b = (const float*)d_in[25];
    const float* c3w = (const float*)d_in[26];   const float* c3b = (const float*)d_in[27];
    const float* tf_w = (const float*)d_in[28];  const float* tf_b = (const float*)d_in[29];
    const float* w1 = (const float*)d_in[30];
    const float* fc1_w = (const float*)d_in[31]; const float* fc1_b = (const float*)d_in[32];
    const float* fc2_w = (const float*)d_in[33]; const float* fc2_b = (const float*)d_in[34];
    const float* outw = (const float*)d_in[35];  const float* outb = (const float*)d_in[36];
    float* out = (float*)d_out;

    const int N = in_sizes[0] / 64;   // 8000
    const int E = in_sizes[4];        // 160000
    const int B = 16, L = 1200;
    const size_t NS = (size_t)N * 576;

    char* wsb = (char*)d_ws;
    size_t off = 0;
    auto allocB = [&](size_t bytes) -> void* {
        void* p = wsb + off;
        off += (bytes + 255) & ~(size_t)255;
        return p;
    };
    auto alloc = [&](size_t elems) -> void* { return allocB(elems * 4); };

    unsigned short* h_bf = (unsigned short*)allocB(2 * NS * 2);
    float* gA    = (float*)alloc(2 * NS);          // L3 f32 out; also hosts L1 split (shorts)
    float* el    = (float*)alloc(2 * (size_t)N * 3);
    float* er    = (float*)alloc(2 * (size_t)N * 3);
    int* rs      = (int*)alloc(2 * (N + 1));
    int* cnt     = (int*)alloc(2 * N);
    int* eidx    = (int*)alloc(2 * E);
    int* gmax    = (int*)alloc(2 * (size_t)B * 576);
    float* gvec  = (float*)alloc(2 * (size_t)B * 128);
    float* sf    = (float*)alloc(2 * (size_t)B * 128);
    float* f1    = (float*)alloc((size_t)B * 512);
    float* f2    = (float*)alloc((size_t)B * 256);
    float4* rec  = (float4*)allocB((size_t)2 * E * 16);
    short* fsplit = (short*)allocB((size_t)2 * 8000 * 128 * 2);
    short* w2t1  = (short*)allocB((size_t)192 * 2 * 64 * 2);
    short* w2t2  = (short*)allocB((size_t)576 * 2 * 192 * 2);
    short* w2t3  = (short*)allocB((size_t)576 * 2 * 576 * 2);
    short* cw1   = (short*)allocB((size_t)128 * 2 * 192 * 2);
    short* cw2   = (short*)allocB((size_t)128 * 2 * 384 * 2);
    short* cw3   = (short*)allocB((size_t)128 * 2 * 384 * 2);
    // UNION: L2 split (2 x 8000 x 1152 shorts = 36.9 MB) aliases TextCNN scratch
    size_t tcnn_elems = 2 * (size_t)B * 128 * (1198 + 397 + 130);
    size_t uni_elems = 2 * NS > tcnn_elems ? 2 * NS : tcnn_elems;
    float* uni = (float*)alloc(uni_elems);
    float* y1 = uni;
    float* y2 = y1 + 2 * (size_t)B * 128 * 1198;
    float* y3 = y2 + 2 * (size_t)B * 128 * 397;
    short* splitA1 = (short*)gA;     // L1 out (2 x 8000 x 384 shorts), consumed by GEMM2
    short* splitA2 = (short*)uni;    // L2 out (2 x 8000 x 1152 shorts), consumed by GEMM3
    (void)ws_size; (void)n_in; (void)out_size; (void)L;

    prep_weights<<<6257, 256, 0, stream>>>(Wg[0], Wg[1], Wg[2], c1w, c2w, c3w,
                                           w2t1, w2t2, w2t3, cw1, cw2, cw3,
                                           feat[0], feat[1], fsplit);
    short* w2t[3] = {w2t1, w2t2, w2t3};

    // --- CSR for both branches (scan zeroes cnt for reuse as fill) ---
    zero_i32<<<(2 * N + 255) / 256, 256, 0, stream>>>(cnt, 2 * N);
    count_edges2<<<(2 * E + 255) / 256, 256, 0, stream>>>(dst[0], dst[1], cnt, N, E);
    scan_block<<<2, 1024, 0, stream>>>(cnt, rs, N);
    scatter_edges2<<<(2 * E + 255) / 256, 256, 0, stream>>>(dst[0], dst[1], rs, cnt, eidx, N, E);

    // --- 3 GAT layers, both branches per dispatch ---
    const int dims[3][3] = {{64, 3, 64}, {192, 3, 192}, {576, 1, 576}};
    const short* aIn = fsplit;
    size_t aBr = (size_t)N * 128;
    for (int ly = 0; ly < 3; ++ly) {
        int K = dims[ly][0], H = dims[ly][1], D = dims[ly][2];
        int HD = H * D;
        gemm_split<<<dim3(HD / 192, N / 32, 2), 256, 0, stream>>>(aIn, w2t[ly], h_bf,
                                                                  N, K, HD, aBr, NS);
        int waves2 = 2 * N * H;
        gat_elr<<<((size_t)waves2 * 64 + 255) / 256, 256, 0, stream>>>(h_bf, al[ly], ar[ly], el, er,
                                                                       N, H, D, NS, (size_t)N * 3);
        gat_alpha<<<dim3((N + 1) / 2, 2), 128, 0, stream>>>(el, er, src[0], src[1], rs, eidx,
                                                            rec, N, H, E, (size_t)N * 3);
        int aggThreads = (((HD >> 2) + 63) / 64) * 64;
        int splitOut = (ly < 2) ? 1 : 0;
        short* osp = (ly == 0) ? splitA1 : splitA2;
        gat_agg<<<dim3(N, 2), aggThreads, 0, stream>>>(
            h_bf, rec, rs, (float4*)gA, osp,
            N, H, D, E, NS, NS / 4, (size_t)N * (size_t)(2 * HD), splitOut);
        aIn = osp;
        aBr = (size_t)N * (size_t)(2 * HD);
    }
    zero_i32<<<(2 * B * 576 + 255) / 256, 256, 0, stream>>>(gmax, 2 * B * 576);
    seg_max_atomic<<<dim3((N + 31) / 32, 2), 256, 0, stream>>>(gA, nid[0], gmax, N, 576,
                                                               NS, (size_t)B * 576);
    linear_wave<<<dim3(32, B, 2), 256, 0, stream>>>((const float*)gmax, fcg_w, fcg_b, gvec,
                                                    576, 128, 1, (size_t)B * 576, (size_t)B * 128);

    // --- TextCNN (MFMA convs; transpose / pools fused into staging) ---
    conv_mfma<<<dim3(19, B, 2), 256, 64 * 68 * 4 + 128 * 72 * 2, stream>>>(
        pad[0], pad[1], cw1, c1b, y1, 64, 1200, 1198, 2, 0,
        0, (size_t)B * 128 * 1198);
    conv_mfma<<<dim3(7, B, 2), 256, 128 * 68 * 4 + 128 * 72 * 2, stream>>>(
        y1, nullptr, cw2, c2b, y2, 128, 399, 397, 1, 1198,
        (size_t)B * 128 * 1198, (size_t)B * 128 * 397);
    conv_mfma<<<dim3(3, B, 2), 256, 128 * 68 * 4 + 128 * 72 * 2, stream>>>(
        y2, nullptr, cw3, c3b, y3, 128, 132, 130, 1, 397,
        (size_t)B * 128 * 397, (size_t)B * 128 * 130);
    pooltf<<<dim3(B, 2), 128, 0, stream>>>(y3, tf_w, tf_b, sf,
                                           (size_t)B * 128 * 130, (size_t)B * 128);

    // --- head MLP (fc1 fused with branch gate) ---
    linear_cat<<<dim3(128, B, 1), 256, 0, stream>>>(gvec, sf, w1, fc1_w, fc1_b, f1, 512, B * 128);
    linear_wave<<<dim3(64, B, 1), 256, 0, stream>>>(f1, fc2_w, fc2_b, f2, 512, 256, 1, 0, 0);
    linear_wave<<<dim3(1, B, 1), 256, 0, stream>>>(f2, outw, outb, out, 256, 1, 2, 0, 0);
}

// Round 6
// 587.100 us; speedup vs baseline: 1.0428x; 1.0428x over previous
//
#include <hip/hip_runtime.h>
#include <hip/hip_bf16.h>
#include <math.h>

#define NEG_SLOPE 0.2f

// ---------------- utility ----------------
__global__ void zero_i32(int* __restrict__ p, int n) {
    int i = blockIdx.x * blockDim.x + threadIdx.x;
    if (i < n) p[i] = 0;
}

// ---------------- CSR build (both branches in one dispatch) ----------------
__global__ void count_edges2(const int* __restrict__ dst0, const int* __restrict__ dst1,
                             int* __restrict__ cnt, int N, int E) {
    int i = blockIdx.x * blockDim.x + threadIdx.x;
    if (i >= 2 * E) return;
    int br = i >= E;
    int j = i - br * E;
    const int* d = br ? dst1 : dst0;
    atomicAdd(&cnt[br * N + d[j]], 1);
}

// scan + zero cnt in place (cnt reused as fill[] by scatter afterwards)
__global__ void scan_block(int* __restrict__ cnt_all, int* __restrict__ rs_all, int N) {
    __shared__ int s[1024];
    int br = blockIdx.x;
    int* cnt = cnt_all + br * N;
    int* rs = rs_all + br * (N + 1);
    int tid = threadIdx.x;
    int running = 0;
    for (int base = 0; base < N; base += 1024) {
        int v = (base + tid < N) ? cnt[base + tid] : 0;
        if (base + tid < N) cnt[base + tid] = 0;
        __syncthreads();
        s[tid] = v;
        __syncthreads();
        for (int off = 1; off < 1024; off <<= 1) {
            int t = (tid >= off) ? s[tid - off] : 0;
            __syncthreads();
            if (tid >= off) s[tid] += t;
            __syncthreads();
        }
        if (base + tid < N) rs[base + tid] = running + s[tid] - v;
        running += s[1023];
    }
    if (tid == 0) rs[N] = running;
}

__global__ void scatter_edges2(const int* __restrict__ dst0, const int* __restrict__ dst1,
                               const int* __restrict__ rs_all, int* __restrict__ fill_all,
                               int* __restrict__ eidx_all, int N, int E) {
    int i = blockIdx.x * blockDim.x + threadIdx.x;
    if (i >= 2 * E) return;
    int br = i >= E;
    int j = i - br * E;
    const int* d = br ? dst1 : dst0;
    int dd = d[j];
    int pos = atomicAdd(&fill_all[br * N + dd], 1);
    eidx_all[br * E + rs_all[br * (N + 1) + dd] + pos] = j;
}

// ---------------- bf16 hi/lo helpers ----------------
__device__ __forceinline__ short f2bf(float x) {
    __hip_bfloat16 h = __float2bfloat16(x);
    return *reinterpret_cast<short*>(&h);
}
__device__ __forceinline__ float bf2f(short s) {
    unsigned int u = ((unsigned int)(unsigned short)s) << 16;
    return __uint_as_float(u);
}
__device__ __forceinline__ float us2f(unsigned short s) {
    return __uint_as_float((unsigned int)s << 16);
}

// ---------------- merged weight prep + feat hi/lo split ---------------------
__device__ __forceinline__ void split_w_elem(const float* W, short* W2t, int K, int N, int idx) {
    int k = idx / N, n = idx - k * N;
    float x = W[idx];
    short hs = f2bf(x);
    short ls = f2bf(x - bf2f(hs));
    size_t base = (size_t)n * 2 * K;
    W2t[base + k] = hs;
    W2t[base + K + k] = ls;
}
__device__ __forceinline__ void split_cw_elem(const float* w, short* w2, int Kp, int idx) {
    int o = idx / Kp, k = idx - o * Kp;
    float x = w[idx];
    short hs = f2bf(x);
    short ls = f2bf(x - bf2f(hs));
    size_t base = (size_t)o * 2 * Kp;
    w2[base + k] = hs;
    w2[base + Kp + k] = ls;
}
__global__ void prep_weights(const float* __restrict__ Wg1, const float* __restrict__ Wg2,
                             const float* __restrict__ Wg3, const float* __restrict__ c1w,
                             const float* __restrict__ c2w, const float* __restrict__ c3w,
                             short* __restrict__ w2t1, short* __restrict__ w2t2,
                             short* __restrict__ w2t3, short* __restrict__ cw1,
                             short* __restrict__ cw2, short* __restrict__ cw3,
                             const float* __restrict__ feat0, const float* __restrict__ feat1,
                             short* __restrict__ fsplit) {
    int idx = blockIdx.x * blockDim.x + threadIdx.x;
    if (idx < 12288)       split_w_elem(Wg1, w2t1, 64, 192, idx);
    else if (idx < 122880) split_w_elem(Wg2, w2t2, 192, 576, idx - 12288);
    else if (idx < 454656) split_w_elem(Wg3, w2t3, 576, 576, idx - 122880);
    else if (idx < 479232) split_cw_elem(c1w, cw1, 192, idx - 454656);
    else if (idx < 528384) split_cw_elem(c2w, cw2, 384, idx - 479232);
    else if (idx < 577536) split_cw_elem(c3w, cw3, 384, idx - 528384);
    else if (idx < 1601536) {
        int j = idx - 577536;           // 0..1023999 = 2 x 8000 x 64
        int br = j >= 512000;
        int e = j - br * 512000;        // n*64 + k
        int n = e >> 6, k = e & 63;
        float x = (br ? feat1 : feat0)[e];
        short hs = f2bf(x);
        short ls = f2bf(x - bf2f(hs));
        short* fs = fsplit + (size_t)br * 1024000;  // 8000 * 128
        fs[n * 128 + k] = hs;
        fs[n * 128 + 64 + k] = ls;
    }
}

// ---------------- MFMA bf16-split GEMM v6 ----------------------------------
// Pre-split hi/lo A ([row][2K]: hi K then lo K), XOR-swizzled unpadded LDS
// (rows = 8 x 16B slots, slot ^= row&7), 64-row M-tile (36 MFMA/K-step),
// register prefetch of the next K-step's global loads overlapped with MFMA.
typedef __attribute__((ext_vector_type(8))) short short8;
typedef __attribute__((ext_vector_type(4))) short short4v;
typedef __attribute__((ext_vector_type(4))) float floatx4;

__global__ __launch_bounds__(256) void gemm_split(const short* __restrict__ Abase,
                                                  const short* __restrict__ Bt,
                                                  unsigned short* __restrict__ Cbf,
                                                  int M, int K, int N,
                                                  size_t aBrStride, size_t cBrStride) {
    __shared__ __align__(16) short sA[64 * 64];
    __shared__ __align__(16) short sB[192 * 64];
    int tid = threadIdx.x;
    int wave = tid >> 6, lane = tid & 63;
    int m = lane & 15, q = lane >> 4;
    int row0 = blockIdx.y << 6;
    int col0 = blockIdx.x * 192;
    const short* A = Abase + blockIdx.z * aBrStride;
    unsigned short* Cbfb = Cbf + blockIdx.z * cBrStride;
    int K2 = K * 2;
    floatx4 acc[4][3];
#pragma unroll
    for (int rt = 0; rt < 4; ++rt)
#pragma unroll
        for (int ct = 0; ct < 3; ++ct) acc[rt][ct] = (floatx4){0.f, 0.f, 0.f, 0.f};

    // per-thread staging addresses (k0-invariant parts)
    int ar = tid >> 3, asl = tid & 7;
    int aKoff = (asl < 4) ? (asl << 3) : (K + ((asl - 4) << 3));
    const short* aSrc0 = A + (size_t)(row0 + ar) * K2 + aKoff;
    const short* aSrc1 = A + (size_t)(row0 + 32 + ar) * K2 + aKoff;
    int aDst0 = (ar << 6) + ((asl ^ (ar & 7)) << 3);
    int aDst1 = aDst0 + 2048;        // (32+ar)&7 == ar&7
    const short* bSrc[6];
    int bDst[6];
#pragma unroll
    for (int p = 0; p < 6; ++p) {
        int t = tid + (p << 8);
        int n = t >> 3, sl = t & 7;
        bSrc[p] = Bt + (size_t)(col0 + n) * K2 +
                  (sl < 4 ? (sl << 3) : (K + ((sl - 4) << 3)));
        bDst[p] = (n << 6) + ((sl ^ (n & 7)) << 3);
    }
    int sw_hi = (q ^ (m & 7)) << 3;
    int sw_lo = ((4 + q) ^ (m & 7)) << 3;

    // prologue prefetch (k0 = 0)
    short8 pa0 = *(const short8*)aSrc0;
    short8 pa1 = *(const short8*)aSrc1;
    short8 pb[6];
#pragma unroll
    for (int p = 0; p < 6; ++p) pb[p] = *(const short8*)bSrc[p];

    for (int k0 = 0; k0 < K; k0 += 32) {
        // write current prefetched tile to LDS
        *(short8*)&sA[aDst0] = pa0;
        *(short8*)&sA[aDst1] = pa1;
#pragma unroll
        for (int p = 0; p < 6; ++p)
            *(short8*)&sB[bDst[p]] = pb[p];
        __syncthreads();
        // issue next tile's global loads (latency hides under MFMA phase)
        int kn = k0 + 32;
        if (kn < K) {
            pa0 = *(const short8*)(aSrc0 + kn);
            pa1 = *(const short8*)(aSrc1 + kn);
#pragma unroll
            for (int p = 0; p < 6; ++p) pb[p] = *(const short8*)(bSrc[p] + kn);
        }
        short8 a_hi[4], a_lo[4];
#pragma unroll
        for (int rt = 0; rt < 4; ++rt) {
            int row = rt * 16 + m;
            a_hi[rt] = *(const short8*)&sA[(row << 6) + sw_hi];
            a_lo[rt] = *(const short8*)&sA[(row << 6) + sw_lo];
        }
#pragma unroll
        for (int ct = 0; ct < 3; ++ct) {
            int bn = wave * 48 + ct * 16 + m;
            short8 b_hi = *(const short8*)&sB[(bn << 6) + sw_hi];
            short8 b_lo = *(const short8*)&sB[(bn << 6) + sw_lo];
#pragma unroll
            for (int rt = 0; rt < 4; ++rt) {
                acc[rt][ct] = __builtin_amdgcn_mfma_f32_16x16x32_bf16(a_hi[rt], b_hi, acc[rt][ct], 0, 0, 0);
                acc[rt][ct] = __builtin_amdgcn_mfma_f32_16x16x32_bf16(a_lo[rt], b_hi, acc[rt][ct], 0, 0, 0);
                acc[rt][ct] = __builtin_amdgcn_mfma_f32_16x16x32_bf16(a_hi[rt], b_lo, acc[rt][ct], 0, 0, 0);
            }
        }
        __syncthreads();
    }
#pragma unroll
    for (int rt = 0; rt < 4; ++rt)
#pragma unroll
        for (int ct = 0; ct < 3; ++ct)
#pragma unroll
            for (int r = 0; r < 4; ++r) {
                size_t idx = (size_t)(row0 + rt * 16 + q * 4 + r) * N + col0 + wave * 48 + ct * 16 + m;
                Cbfb[idx] = (unsigned short)f2bf(acc[rt][ct][r]);
            }
    (void)M;
}

// ---------------- GAT pieces (branch-fused; h in bf16) ----------------
__global__ void gat_elr(const unsigned short* __restrict__ h, const float* __restrict__ al,
                        const float* __restrict__ ar, float* __restrict__ el,
                        float* __restrict__ er, int N, int H, int D,
                        size_t hBr, size_t eBr) {
    int wid = (blockIdx.x * blockDim.x + threadIdx.x) >> 6;
    int lane = threadIdx.x & 63;
    if (wid >= 2 * N * H) return;
    int br = wid / (N * H);
    int loc = wid - br * N * H;
    int n = loc / H, hh = loc - n * H;
    const unsigned short* hp = h + br * hBr + ((size_t)n * H + hh) * D;
    const float* alp = al + (size_t)hh * D;
    const float* arp = ar + (size_t)hh * D;
    float sl = 0.f, sr = 0.f;
    for (int d = lane; d < D; d += 64) {
        float v = us2f(hp[d]);
        sl += v * alp[d];
        sr += v * arp[d];
    }
    for (int off = 32; off > 0; off >>= 1) {
        sl += __shfl_down(sl, off, 64);
        sr += __shfl_down(sr, off, 64);
    }
    if (lane == 0) { el[br * eBr + loc] = sl; er[br * eBr + loc] = sr; }
}

__device__ __forceinline__ float lrelu(float v) {
    return (v > 0.f) ? v : NEG_SLOPE * v;
}

// ---------------- per-node softmax -> per-edge records {src, a0,a1,a2} ------
__global__ __launch_bounds__(128) void gat_alpha(
        const float* __restrict__ el_all, const float* __restrict__ er_all,
        const int* __restrict__ src0, const int* __restrict__ src1,
        const int* __restrict__ rs_all, const int* __restrict__ eidx_all,
        float4* __restrict__ rec_all, int N, int H, int E, size_t eBr) {
    int n = blockIdx.x * 2 + (threadIdx.x >> 6);
    int br = blockIdx.y;
    if (n >= N) return;
    const int* src = br ? src1 : src0;
    const int* rs = rs_all + br * (N + 1);
    const int* eidx = eidx_all + br * E;
    const float* el = el_all + br * eBr;
    const float* er = er_all + br * eBr;
    float4* rec = rec_all + (size_t)br * E;
    int lane = threadIdx.x & 63;
    int s0 = rs[n], s1 = rs[n + 1];
    int deg = s1 - s0;
    if (deg <= 0) return;
    float ern0 = er[n * H + 0];
    float ern1 = (H > 1) ? er[n * H + 1] : 0.f;
    float ern2 = (H > 2) ? er[n * H + 2] : 0.f;
    if (deg <= 64) {
        int s = 0;
        float v0 = -INFINITY, v1 = -INFINITY, v2 = -INFINITY;
        if (lane < deg) {
            int e = eidx[s0 + lane];
            s = src[e];
            v0 = lrelu(el[s * H + 0] + ern0);
            if (H > 1) {
                v1 = lrelu(el[s * H + 1] + ern1);
                v2 = lrelu(el[s * H + 2] + ern2);
            }
        }
        float m0 = v0, m1 = v1, m2 = v2;
#pragma unroll
        for (int off = 32; off > 0; off >>= 1) {
            m0 = fmaxf(m0, __shfl_xor(m0, off, 64));
            m1 = fmaxf(m1, __shfl_xor(m1, off, 64));
            m2 = fmaxf(m2, __shfl_xor(m2, off, 64));
        }
        float ex0 = (lane < deg) ? expf(v0 - m0) : 0.f;
        float ex1 = (lane < deg && H > 1) ? expf(v1 - m1) : 0.f;
        float ex2 = (lane < deg && H > 2) ? expf(v2 - m2) : 0.f;
        float d0 = ex0, d1 = ex1, d2 = ex2;
#pragma unroll
        for (int off = 32; off > 0; off >>= 1) {
            d0 += __shfl_xor(d0, off, 64);
            d1 += __shfl_xor(d1, off, 64);
            d2 += __shfl_xor(d2, off, 64);
        }
        if (lane < deg) {
            float4 r;
            r.x = __int_as_float(s);
            r.y = ex0 / d0;
            r.z = (H > 1) ? ex1 / d1 : 0.f;
            r.w = (H > 2) ? ex2 / d2 : 0.f;
            rec[s0 + lane] = r;
        }
    } else {
        float m0 = -INFINITY, m1 = -INFINITY, m2 = -INFINITY;
        for (int j = s0 + lane; j < s1; j += 64) {
            int e = eidx[j], s = src[e];
            m0 = fmaxf(m0, lrelu(el[s * H + 0] + ern0));
            if (H > 1) {
                m1 = fmaxf(m1, lrelu(el[s * H + 1] + ern1));
                m2 = fmaxf(m2, lrelu(el[s * H + 2] + ern2));
            }
        }
#pragma unroll
        for (int off = 32; off > 0; off >>= 1) {
            m0 = fmaxf(m0, __shfl_xor(m0, off, 64));
            m1 = fmaxf(m1, __shfl_xor(m1, off, 64));
            m2 = fmaxf(m2, __shfl_xor(m2, off, 64));
        }
        float d0 = 0.f, d1 = 0.f, d2 = 0.f;
        for (int j = s0 + lane; j < s1; j += 64) {
            int e = eidx[j], s = src[e];
            d0 += expf(lrelu(el[s * H + 0] + ern0) - m0);
            if (H > 1) {
                d1 += expf(lrelu(el[s * H + 1] + ern1) - m1);
                d2 += expf(lrelu(el[s * H + 2] + ern2) - m2);
            }
        }
#pragma unroll
        for (int off = 32; off > 0; off >>= 1) {
            d0 += __shfl_xor(d0, off, 64);
            d1 += __shfl_xor(d1, off, 64);
            d2 += __shfl_xor(d2, off, 64);
        }
        float i0 = 1.f / d0;
        float i1 = (H > 1) ? 1.f / d1 : 0.f;
        float i2 = (H > 2) ? 1.f / d2 : 0.f;
        for (int j = s0 + lane; j < s1; j += 64) {
            int e = eidx[j], s = src[e];
            float4 r;
            r.x = __int_as_float(s);
            r.y = expf(lrelu(el[s * H + 0] + ern0) - m0) * i0;
            r.z = (H > 1) ? expf(lrelu(el[s * H + 1] + ern1) - m1) * i1 : 0.f;
            r.w = (H > 2) ? expf(lrelu(el[s * H + 2] + ern2) - m2) * i2 : 0.f;
            rec[j] = r;
        }
    }
}

// ---------------- full-row aggregation from precomputed records -------------
// splitOut=1: write hi/lo bf16 planes ([n][2HD]: hi HD then lo HD) for the
// next layer's GEMM A operand. splitOut=0: write f32 (layer 3 -> seg_max).
__global__ __launch_bounds__(192) void gat_agg(
        const unsigned short* __restrict__ hb_all, const float4* __restrict__ rec_all,
        const int* __restrict__ rs_all, float4* __restrict__ out4_all,
        short* __restrict__ osplit_all,
        int N, int H, int D, int E, size_t hBr, size_t o4Br, size_t osBr, int splitOut) {
    int n = blockIdx.x;
    int br = blockIdx.y;
    int HD = H * D;
    int HD4 = HD >> 2;
    int tid = threadIdx.x;
    if (tid >= HD4) return;
    int hh = (tid << 2) / D;
    const unsigned short* hb = hb_all + br * hBr;
    const float4* rec = rec_all + (size_t)br * E;
    const int* rs = rs_all + br * (N + 1);
    int s0 = rs[n], s1 = rs[n + 1];
    int ch = tid << 2;
    float4 a0 = {0.f, 0.f, 0.f, 0.f};
    float4 a1 = {0.f, 0.f, 0.f, 0.f};
    float4 a2 = {0.f, 0.f, 0.f, 0.f};
    float4 a3 = {0.f, 0.f, 0.f, 0.f};
    int i = s0;
    for (; i + 3 < s1; i += 4) {
        float4 r0 = rec[i];
        float4 r1 = rec[i + 1];
        float4 r2 = rec[i + 2];
        float4 r3 = rec[i + 3];
        int sA = __float_as_int(r0.x);
        int sB = __float_as_int(r1.x);
        int sC = __float_as_int(r2.x);
        int sD = __float_as_int(r3.x);
        ushort4 h0 = *(const ushort4*)&hb[(size_t)sA * HD + ch];
        ushort4 h1 = *(const ushort4*)&hb[(size_t)sB * HD + ch];
        ushort4 h2 = *(const ushort4*)&hb[(size_t)sC * HD + ch];
        ushort4 h3 = *(const ushort4*)&hb[(size_t)sD * HD + ch];
        float w0 = (hh == 0) ? r0.y : ((hh == 1) ? r0.z : r0.w);
        float w1 = (hh == 0) ? r1.y : ((hh == 1) ? r1.z : r1.w);
        float w2 = (hh == 0) ? r2.y : ((hh == 1) ? r2.z : r2.w);
        float w3 = (hh == 0) ? r3.y : ((hh == 1) ? r3.z : r3.w);
        a0.x += w0 * us2f(h0.x); a0.y += w0 * us2f(h0.y);
        a0.z += w0 * us2f(h0.z); a0.w += w0 * us2f(h0.w);
        a1.x += w1 * us2f(h1.x); a1.y += w1 * us2f(h1.y);
        a1.z += w1 * us2f(h1.z); a1.w += w1 * us2f(h1.w);
        a2.x += w2 * us2f(h2.x); a2.y += w2 * us2f(h2.y);
        a2.z += w2 * us2f(h2.z); a2.w += w2 * us2f(h2.w);
        a3.x += w3 * us2f(h3.x); a3.y += w3 * us2f(h3.y);
        a3.z += w3 * us2f(h3.z); a3.w += w3 * us2f(h3.w);
    }
    for (; i < s1; ++i) {
        float4 r0 = rec[i];
        int sA = __float_as_int(r0.x);
        ushort4 h0 = *(const ushort4*)&hb[(size_t)sA * HD + ch];
        float w0 = (hh == 0) ? r0.y : ((hh == 1) ? r0.z : r0.w);
        a0.x += w0 * us2f(h0.x); a0.y += w0 * us2f(h0.y);
        a0.z += w0 * us2f(h0.z); a0.w += w0 * us2f(h0.w);
    }
    float4 o;
    o.x = fmaxf(a0.x + a1.x + a2.x + a3.x, 0.f);
    o.y = fmaxf(a0.y + a1.y + a2.y + a3.y, 0.f);
    o.z = fmaxf(a0.z + a1.z + a2.z + a3.z, 0.f);
    o.w = fmaxf(a0.w + a1.w + a2.w + a3.w, 0.f);
    if (splitOut) {
        short* os = osplit_all + br * osBr;
        int HD2 = HD << 1;
        short4v hi, lo;
        hi[0] = f2bf(o.x); lo[0] = f2bf(o.x - bf2f(hi[0]));
        hi[1] = f2bf(o.y); lo[1] = f2bf(o.y - bf2f(hi[1]));
        hi[2] = f2bf(o.z); lo[2] = f2bf(o.z - bf2f(hi[2]));
        hi[3] = f2bf(o.w); lo[3] = f2bf(o.w - bf2f(hi[3]));
        *(short4v*)&os[(size_t)n * HD2 + ch] = hi;
        *(short4v*)&os[(size_t)n * HD2 + HD + ch] = lo;
    } else {
        out4_all[br * o4Br + (size_t)n * HD4 + tid] = o;
    }
}

// Graph max-readout (post-ReLU >=0) via int-bitcast atomicMax. grid.y = branch.
__global__ void seg_max_atomic(const float* __restrict__ g_all, const int* __restrict__ nid,
                               int* __restrict__ out_all, int N, int C,
                               size_t gBr, size_t oBr) {
    int br = blockIdx.y;
    const float* g = g_all + br * gBr;
    int* out = out_all + br * oBr;
    int n0 = blockIdx.x << 5;
    int n1 = n0 + 32; if (n1 > N) n1 = N;
    if (n0 >= N) return;
    for (int c = threadIdx.x; c < C; c += blockDim.x) {
        int cur = nid[n0];
        float m = 0.f;
        for (int n = n0; n < n1; ++n) {
            int gid = nid[n];
            if (gid != cur) {
                atomicMax(&out[cur * C + c], __float_as_int(m));
                cur = gid; m = 0.f;
            }
            m = fmaxf(m, g[(size_t)n * C + c]);
        }
        atomicMax(&out[cur * C + c], __float_as_int(m));
    }
}

// ---------------- small dense layers (grid.z = branch; strides may be 0) ----
__global__ void linear_wave(const float* __restrict__ in, const float* __restrict__ W,
                            const float* __restrict__ bias, float* __restrict__ out,
                            int K, int O, int act, size_t inBr, size_t outBr) {
    int o = blockIdx.x * 4 + (threadIdx.x >> 6);
    int b = blockIdx.y;
    int lane = threadIdx.x & 63;
    if (o >= O) return;
    const float* ip = in + blockIdx.z * inBr + (size_t)b * K;
    float acc = 0.f;
    for (int k = lane; k < K; k += 64)
        acc += ip[k] * W[(size_t)k * O + o];
    for (int off = 32; off > 0; off >>= 1)
        acc += __shfl_down(acc, off, 64);
    if (lane == 0) {
        acc += bias[o];
        if (act == 1) acc = fmaxf(acc, 0.f);
        else if (act == 2) acc = 1.f / (1.f + expf(-acc));
        out[blockIdx.z * outBr + (size_t)b * O + o] = acc;
    }
}

// fc1 fused with the branch gate (K = 256 fixed).
__global__ void linear_cat(const float* __restrict__ gvec, const float* __restrict__ sf,
                           const float* __restrict__ w1, const float* __restrict__ W,
                           const float* __restrict__ bias, float* __restrict__ out,
                           int O, int B128) {
    int o = blockIdx.x * 4 + (threadIdx.x >> 6);
    int b = blockIdx.y;
    int lane = threadIdx.x & 63;
    if (o >= 512) return;
    float w = 1.f / (1.f + expf(-w1[0]));
    float acc = 0.f;
    for (int k = lane; k < 256; k += 64) {
        int br = k >> 7, c = k & 127;
        float v = (1.f - w) * gvec[br * B128 + b * 128 + c] + w * sf[br * B128 + b * 128 + c];
        acc += v * W[(size_t)k * 512 + o];
    }
    for (int off = 32; off > 0; off >>= 1)
        acc += __shfl_down(acc, off, 64);
    if (lane == 0)
        out[(size_t)b * 512 + o] = fmaxf(acc + bias[o], 0.f);
    (void)O;
}

// ---------------- conv1d k=3 as MFMA (im2col on the fly) --------------------
__global__ __launch_bounds__(256) void conv_mfma(const float* __restrict__ x,
                                                 const float* __restrict__ x1,
                                                 const short* __restrict__ w2,
                                                 const float* __restrict__ bias,
                                                 float* __restrict__ y,
                                                 int Cin, int Lin, int Lout,
                                                 int mode, int srcLen,
                                                 size_t xBr, size_t yBr) {
    extern __shared__ __align__(16) char smem[];
    float* sx = (float*)smem;                          // Cin x 68 fp32
    short* sB = (short*)(smem + (size_t)Cin * 68 * 4); // 128 x 72 shorts
    int Kp = Cin * 3;
    int K2 = Kp * 2;
    int b = blockIdx.y;
    float* yb = y + blockIdx.z * yBr + (size_t)b * 128 * Lout;
    int l0 = blockIdx.x << 6;
    int tid = threadIdx.x;
    int wave = tid >> 6, lane = tid & 63;
    int m = lane & 15, q = lane >> 4;
    int wrow = (wave & 1) << 5;
    int wcol = (wave >> 1) << 6;
    int loadL = Lin - l0; if (loadL > 66) loadL = 66;
    if (mode == 2) {
        const float* pb = (blockIdx.z ? x1 : x) + (size_t)b * 1200 * 64;
        for (int t = tid; t < loadL * 64; t += 256) {
            int i = t >> 6, c = t & 63;
            sx[c * 68 + i] = pb[(size_t)(l0 + i) * 64 + c];
        }
    } else if (mode == 1) {
        const float* xb = x + blockIdx.z * xBr + (size_t)b * Cin * srcLen;
        for (int t = tid; t < Cin * loadL; t += 256) {
            int c = t / loadL, i = t - c * loadL;
            const float* row = &xb[(size_t)c * srcLen + 3 * (l0 + i)];
            sx[c * 68 + i] = fmaxf(fmaxf(row[0], row[1]), row[2]);
        }
    } else {
        const float* xb = x + blockIdx.z * xBr + (size_t)b * Cin * srcLen;
        for (int t = tid; t < Cin * loadL; t += 256) {
            int c = t / loadL, i = t - c * loadL;
            sx[c * 68 + i] = xb[(size_t)c * srcLen + l0 + i];
        }
    }
    floatx4 acc[2][4];
#pragma unroll
    for (int rt = 0; rt < 2; ++rt)
#pragma unroll
        for (int ct = 0; ct < 4; ++ct) acc[rt][ct] = (floatx4){0.f, 0.f, 0.f, 0.f};

    for (int k0 = 0; k0 < Kp; k0 += 32) {
#pragma unroll
        for (int p = 0; p < 4; ++p) {
            int t = tid + (p << 8);
            int o = t >> 3, slot = t & 7;
            int srcoff = k0 + ((slot & 3) << 3) + ((slot >= 4) ? Kp : 0);
            *(float4*)&sB[o * 72 + (slot << 3)] = *(const float4*)&w2[(size_t)o * K2 + srcoff];
        }
        __syncthreads();
        short8 a_hi[2], a_lo[2];
#pragma unroll
        for (int rt = 0; rt < 2; ++rt) {
            int pos = wrow + rt * 16 + m;
#pragma unroll
            for (int kk = 0; kk < 8; ++kk) {
                int k = k0 + q * 8 + kk;
                int c = k / 3, j = k - c * 3;
                float v = sx[c * 68 + pos + j];
                short hv = f2bf(v);
                a_hi[rt][kk] = hv;
                a_lo[rt][kk] = f2bf(v - bf2f(hv));
            }
        }
#pragma unroll
        for (int ct = 0; ct < 4; ++ct) {
            short8 b_hi = *(const short8*)&sB[(wcol + ct * 16 + m) * 72 + q * 8];
            short8 b_lo = *(const short8*)&sB[(wcol + ct * 16 + m) * 72 + 32 + q * 8];
#pragma unroll
            for (int rt = 0; rt < 2; ++rt) {
                acc[rt][ct] = __builtin_amdgcn_mfma_f32_16x16x32_bf16(a_hi[rt], b_hi, acc[rt][ct], 0, 0, 0);
                acc[rt][ct] = __builtin_amdgcn_mfma_f32_16x16x32_bf16(a_lo[rt], b_hi, acc[rt][ct], 0, 0, 0);
                acc[rt][ct] = __builtin_amdgcn_mfma_f32_16x16x32_bf16(a_hi[rt], b_lo, acc[rt][ct], 0, 0, 0);
            }
        }
        __syncthreads();
    }
#pragma unroll
    for (int ct = 0; ct < 4; ++ct) {
        int o = wcol + ct * 16 + m;
        float bv = bias[o];
#pragma unroll
        for (int rt = 0; rt < 2; ++rt)
#pragma unroll
            for (int r = 0; r < 4; ++r) {
                int pos = wrow + rt * 16 + q * 4 + r;
                if (l0 + pos < Lout)
                    yb[(size_t)o * Lout + l0 + pos] = acc[rt][ct][r] + bv;
            }
    }
}

// fused: global 130-max-pool over y3 + tf linear + ReLU. block per (b, br).
__global__ void pooltf(const float* __restrict__ y3, const float* __restrict__ tf_w,
                       const float* __restrict__ tf_b, float* __restrict__ sf,
                       size_t yBr, size_t sfBr) {
    __shared__ float s_sp[128];
    int b = blockIdx.x, br = blockIdx.y;
    const float* yb = y3 + br * yBr + (size_t)b * 128 * 130;
    int c = threadIdx.x;
    float mx = -INFINITY;
    for (int l = 0; l < 130; ++l) mx = fmaxf(mx, yb[(size_t)c * 130 + l]);
    s_sp[c] = mx;
    __syncthreads();
    int o = threadIdx.x;
    float acc = tf_b[o];
    for (int k = 0; k < 128; ++k) acc += s_sp[k] * tf_w[(size_t)k * 128 + o];
    sf[br * sfBr + (size_t)b * 128 + o] = fmaxf(acc, 0.f);
}

// ---------------- host ----------------
extern "C" void kernel_launch(void* const* d_in, const int* in_sizes, int n_in,
                              void* d_out, int out_size, void* d_ws, size_t ws_size,
                              hipStream_t stream) {
    const float* feat[2] = {(const float*)d_in[0], (const float*)d_in[1]};
    const float* pad[2]  = {(const float*)d_in[2], (const float*)d_in[3]};
    const int* src[2]    = {(const int*)d_in[4], (const int*)d_in[6]};
    const int* dst[2]    = {(const int*)d_in[5], (const int*)d_in[7]};
    const int* nid[2]    = {(const int*)d_in[8], (const int*)d_in[9]};
    const float* Wg[3]   = {(const float*)d_in[11], (const float*)d_in[14], (const float*)d_in[17]};
    const float* al[3]   = {(const float*)d_in[12], (const float*)d_in[15], (const float*)d_in[18]};
    const float* ar[3]   = {(const float*)d_in[13], (const float*)d_in[16], (const float*)d_in[19]};
    const float* fcg_w = (const float*)d_in[20]; const float* fcg_b = (const float*)d_in[21];
    const float* c1w = (const float*)d_in[22];   const float* c1b = (const float*)d_in[23];
    const float* c2w = (const float*)d_in[24];   const float* c2b = (const float*)d_in[25];
    const float* c3w = (const float*)d_in[26];   const float* c3b = (const float*)d_in[27];
    const float* tf_w = (const float*)d_in[28];  const float* tf_b = (const float*)d_in[29];
    const float* w1 = (const float*)d_in[30];
    const float* fc1_w = (const float*)d_in[31]; const float* fc1_b = (const float*)d_in[32];
    const float* fc2_w = (const float*)d_in[33]; const float* fc2_b = (const float*)d_in[34];
    const float* outw = (const float*)d_in[35];  const float* outb = (const float*)d_in[36];
    float* out = (float*)d_out;

    const int N = in_sizes[0] / 64;   // 8000
    const int E = in_sizes[4];        // 160000
    const int B = 16, L = 1200;
    const size_t NS = (size_t)N * 576;

    char* wsb = (char*)d_ws;
    size_t off = 0;
    auto allocB = [&](size_t bytes) -> void* {
        void* p = wsb + off;
        off += (bytes + 255) & ~(size_t)255;
        return p;
    };
    auto alloc = [&](size_t elems) -> void* { return allocB(elems * 4); };

    unsigned short* h_bf = (unsigned short*)allocB(2 * NS * 2);
    float* gA    = (float*)alloc(2 * NS);          // L3 f32 out; also hosts L1 split (shorts)
    float* el    = (float*)alloc(2 * (size_t)N * 3);
    float* er    = (float*)alloc(2 * (size_t)N * 3);
    int* rs      = (int*)alloc(2 * (N + 1));
    int* cnt     = (int*)alloc(2 * N);
    int* eidx    = (int*)alloc(2 * E);
    int* gmax    = (int*)alloc(2 * (size_t)B * 576);
    float* gvec  = (float*)alloc(2 * (size_t)B * 128);
    float* sf    = (float*)alloc(2 * (size_t)B * 128);
    float* f1    = (float*)alloc((size_t)B * 512);
    float* f2    = (float*)alloc((size_t)B * 256);
    float4* rec  = (float4*)allocB((size_t)2 * E * 16);
    short* fsplit = (short*)allocB((size_t)2 * 8000 * 128 * 2);
    short* w2t1  = (short*)allocB((size_t)192 * 2 * 64 * 2);
    short* w2t2  = (short*)allocB((size_t)576 * 2 * 192 * 2);
    short* w2t3  = (short*)allocB((size_t)576 * 2 * 576 * 2);
    short* cw1   = (short*)allocB((size_t)128 * 2 * 192 * 2);
    short* cw2   = (short*)allocB((size_t)128 * 2 * 384 * 2);
    short* cw3   = (short*)allocB((size_t)128 * 2 * 384 * 2);
    // UNION: L2 split (2 x 8000 x 1152 shorts = 36.9 MB) aliases TextCNN scratch
    size_t tcnn_elems = 2 * (size_t)B * 128 * (1198 + 397 + 130);
    size_t uni_elems = 2 * NS > tcnn_elems ? 2 * NS : tcnn_elems;
    float* uni = (float*)alloc(uni_elems);
    float* y1 = uni;
    float* y2 = y1 + 2 * (size_t)B * 128 * 1198;
    float* y3 = y2 + 2 * (size_t)B * 128 * 397;
    short* splitA1 = (short*)gA;     // L1 out (2 x 8000 x 384 shorts), consumed by GEMM2
    short* splitA2 = (short*)uni;    // L2 out (2 x 8000 x 1152 shorts), consumed by GEMM3
    (void)ws_size; (void)n_in; (void)out_size; (void)L;

    prep_weights<<<6257, 256, 0, stream>>>(Wg[0], Wg[1], Wg[2], c1w, c2w, c3w,
                                           w2t1, w2t2, w2t3, cw1, cw2, cw3,
                                           feat[0], feat[1], fsplit);
    short* w2t[3] = {w2t1, w2t2, w2t3};

    // --- CSR for both branches (scan zeroes cnt for reuse as fill) ---
    zero_i32<<<(2 * N + 255) / 256, 256, 0, stream>>>(cnt, 2 * N);
    count_edges2<<<(2 * E + 255) / 256, 256, 0, stream>>>(dst[0], dst[1], cnt, N, E);
    scan_block<<<2, 1024, 0, stream>>>(cnt, rs, N);
    scatter_edges2<<<(2 * E + 255) / 256, 256, 0, stream>>>(dst[0], dst[1], rs, cnt, eidx, N, E);

    // --- 3 GAT layers, both branches per dispatch ---
    const int dims[3][3] = {{64, 3, 64}, {192, 3, 192}, {576, 1, 576}};
    const short* aIn = fsplit;
    size_t aBr = (size_t)N * 128;
    for (int ly = 0; ly < 3; ++ly) {
        int K = dims[ly][0], H = dims[ly][1], D = dims[ly][2];
        int HD = H * D;
        gemm_split<<<dim3(HD / 192, N / 64, 2), 256, 0, stream>>>(aIn, w2t[ly], h_bf,
                                                                  N, K, HD, aBr, NS);
        int waves2 = 2 * N * H;
        gat_elr<<<((size_t)waves2 * 64 + 255) / 256, 256, 0, stream>>>(h_bf, al[ly], ar[ly], el, er,
                                                                       N, H, D, NS, (size_t)N * 3);
        gat_alpha<<<dim3((N + 1) / 2, 2), 128, 0, stream>>>(el, er, src[0], src[1], rs, eidx,
                                                            rec, N, H, E, (size_t)N * 3);
        int aggThreads = (((HD >> 2) + 63) / 64) * 64;
        int splitOut = (ly < 2) ? 1 : 0;
        short* osp = (ly == 0) ? splitA1 : splitA2;
        gat_agg<<<dim3(N, 2), aggThreads, 0, stream>>>(
            h_bf, rec, rs, (float4*)gA, osp,
            N, H, D, E, NS, NS / 4, (size_t)N * (size_t)(2 * HD), splitOut);
        aIn = osp;
        aBr = (size_t)N * (size_t)(2 * HD);
    }
    zero_i32<<<(2 * B * 576 + 255) / 256, 256, 0, stream>>>(gmax, 2 * B * 576);
    seg_max_atomic<<<dim3((N + 31) / 32, 2), 256, 0, stream>>>(gA, nid[0], gmax, N, 576,
                                                               NS, (size_t)B * 576);
    linear_wave<<<dim3(32, B, 2), 256, 0, stream>>>((const float*)gmax, fcg_w, fcg_b, gvec,
                                                    576, 128, 1, (size_t)B * 576, (size_t)B * 128);

    // --- TextCNN (MFMA convs; transpose / pools fused into staging) ---
    conv_mfma<<<dim3(19, B, 2), 256, 64 * 68 * 4 + 128 * 72 * 2, stream>>>(
        pad[0], pad[1], cw1, c1b, y1, 64, 1200, 1198, 2, 0,
        0, (size_t)B * 128 * 1198);
    conv_mfma<<<dim3(7, B, 2), 256, 128 * 68 * 4 + 128 * 72 * 2, stream>>>(
        y1, nullptr, cw2, c2b, y2, 128, 399, 397, 1, 1198,
        (size_t)B * 128 * 1198, (size_t)B * 128 * 397);
    conv_mfma<<<dim3(3, B, 2), 256, 128 * 68 * 4 + 128 * 72 * 2, stream>>>(
        y2, nullptr, cw3, c3b, y3, 128, 132, 130, 1, 397,
        (size_t)B * 128 * 397, (size_t)B * 128 * 130);
    pooltf<<<dim3(B, 2), 128, 0, stream>>>(y3, tf_w, tf_b, sf,
                                           (size_t)B * 128 * 130, (size_t)B * 128);

    // --- head MLP (fc1 fused with branch gate) ---
    linear_cat<<<dim3(128, B, 1), 256, 0, stream>>>(gvec, sf, w1, fc1_w, fc1_b, f1, 512, B * 128);
    linear_wave<<<dim3(64, B, 1), 256, 0, stream>>>(f1, fc2_w, fc2_b, f2, 512, 256, 1, 0, 0);
    linear_wave<<<dim3(1, B, 1), 256, 0, stream>>>(f2, outw, outb, out, 256, 1, 2, 0, 0);
}

// Round 7
// 574.892 us; speedup vs baseline: 1.0650x; 1.0212x over previous
//
#include <hip/hip_runtime.h>
#include <hip/hip_bf16.h>
#include <math.h>

#define NEG_SLOPE 0.2f

// ---------------- utility ----------------
__global__ void zero_i32(int* __restrict__ p, int n) {
    int i = blockIdx.x * blockDim.x + threadIdx.x;
    if (i < n) p[i] = 0;
}

// ---------------- CSR build (both branches in one dispatch) ----------------
__global__ void count_edges2(const int* __restrict__ dst0, const int* __restrict__ dst1,
                             int* __restrict__ cnt, int N, int E) {
    int i = blockIdx.x * blockDim.x + threadIdx.x;
    if (i >= 2 * E) return;
    int br = i >= E;
    int j = i - br * E;
    const int* d = br ? dst1 : dst0;
    atomicAdd(&cnt[br * N + d[j]], 1);
}

// scan + zero cnt in place (cnt reused as fill[] by scatter afterwards)
__global__ void scan_block(int* __restrict__ cnt_all, int* __restrict__ rs_all, int N) {
    __shared__ int s[1024];
    int br = blockIdx.x;
    int* cnt = cnt_all + br * N;
    int* rs = rs_all + br * (N + 1);
    int tid = threadIdx.x;
    int running = 0;
    for (int base = 0; base < N; base += 1024) {
        int v = (base + tid < N) ? cnt[base + tid] : 0;
        if (base + tid < N) cnt[base + tid] = 0;
        __syncthreads();
        s[tid] = v;
        __syncthreads();
        for (int off = 1; off < 1024; off <<= 1) {
            int t = (tid >= off) ? s[tid - off] : 0;
            __syncthreads();
            if (tid >= off) s[tid] += t;
            __syncthreads();
        }
        if (base + tid < N) rs[base + tid] = running + s[tid] - v;
        running += s[1023];
    }
    if (tid == 0) rs[N] = running;
}

__global__ void scatter_edges2(const int* __restrict__ dst0, const int* __restrict__ dst1,
                               const int* __restrict__ rs_all, int* __restrict__ fill_all,
                               int* __restrict__ eidx_all, int N, int E) {
    int i = blockIdx.x * blockDim.x + threadIdx.x;
    if (i >= 2 * E) return;
    int br = i >= E;
    int j = i - br * E;
    const int* d = br ? dst1 : dst0;
    int dd = d[j];
    int pos = atomicAdd(&fill_all[br * N + dd], 1);
    eidx_all[br * E + rs_all[br * (N + 1) + dd] + pos] = j;
}

// ---------------- bf16 hi/lo helpers ----------------
__device__ __forceinline__ short f2bf(float x) {
    __hip_bfloat16 h = __float2bfloat16(x);
    return *reinterpret_cast<short*>(&h);
}
__device__ __forceinline__ float bf2f(short s) {
    unsigned int u = ((unsigned int)(unsigned short)s) << 16;
    return __uint_as_float(u);
}
__device__ __forceinline__ float us2f(unsigned short s) {
    return __uint_as_float((unsigned int)s << 16);
}

// ---------------- merged weight prep + feat hi/lo split ---------------------
__device__ __forceinline__ void split_w_elem(const float* W, short* W2t, int K, int N, int idx) {
    int k = idx / N, n = idx - k * N;
    float x = W[idx];
    short hs = f2bf(x);
    short ls = f2bf(x - bf2f(hs));
    size_t base = (size_t)n * 2 * K;
    W2t[base + k] = hs;
    W2t[base + K + k] = ls;
}
__device__ __forceinline__ void split_cw_elem(const float* w, short* w2, int Kp, int idx) {
    int o = idx / Kp, k = idx - o * Kp;
    float x = w[idx];
    short hs = f2bf(x);
    short ls = f2bf(x - bf2f(hs));
    size_t base = (size_t)o * 2 * Kp;
    w2[base + k] = hs;
    w2[base + Kp + k] = ls;
}
__global__ void prep_weights(const float* __restrict__ Wg1, const float* __restrict__ Wg2,
                             const float* __restrict__ Wg3, const float* __restrict__ c1w,
                             const float* __restrict__ c2w, const float* __restrict__ c3w,
                             short* __restrict__ w2t1, short* __restrict__ w2t2,
                             short* __restrict__ w2t3, short* __restrict__ cw1,
                             short* __restrict__ cw2, short* __restrict__ cw3,
                             const float* __restrict__ feat0, const float* __restrict__ feat1,
                             short* __restrict__ fsplit) {
    int idx = blockIdx.x * blockDim.x + threadIdx.x;
    if (idx < 12288)       split_w_elem(Wg1, w2t1, 64, 192, idx);
    else if (idx < 122880) split_w_elem(Wg2, w2t2, 192, 576, idx - 12288);
    else if (idx < 454656) split_w_elem(Wg3, w2t3, 576, 576, idx - 122880);
    else if (idx < 479232) split_cw_elem(c1w, cw1, 192, idx - 454656);
    else if (idx < 528384) split_cw_elem(c2w, cw2, 384, idx - 479232);
    else if (idx < 577536) split_cw_elem(c3w, cw3, 384, idx - 528384);
    else if (idx < 1601536) {
        int j = idx - 577536;           // 0..1023999 = 2 x 8000 x 64
        int br = j >= 512000;
        int e = j - br * 512000;        // n*64 + k
        int n = e >> 6, k = e & 63;
        float x = (br ? feat1 : feat0)[e];
        short hs = f2bf(x);
        short ls = f2bf(x - bf2f(hs));
        short* fs = fsplit + (size_t)br * 1024000;  // 8000 * 128
        fs[n * 128 + k] = hs;
        fs[n * 128 + 64 + k] = ls;
    }
}

// ---------------- MFMA bf16-split GEMM v7 ----------------------------------
// Pre-split hi/lo A ([row][2K]), XOR-swizzled LDS reads. Staging now via
// global_load_lds (16B/lane, wave-uniform LDS base): linear LDS dest +
// inverse-swizzled per-lane GLOBAL source (rule: swizzle both sides via the
// source permutation since gload_lds writes base+lane*16 linearly).
typedef __attribute__((ext_vector_type(8))) short short8;
typedef __attribute__((ext_vector_type(4))) short short4v;
typedef __attribute__((ext_vector_type(4))) float floatx4;

__device__ __forceinline__ void gll16(const short* g, short* l) {
    __builtin_amdgcn_global_load_lds(
        (__attribute__((address_space(1))) void*)(short*)g,
        (__attribute__((address_space(3))) void*)l, 16, 0, 0);
}

__global__ __launch_bounds__(256) void gemm_split(const short* __restrict__ Abase,
                                                  const short* __restrict__ Bt,
                                                  unsigned short* __restrict__ Cbf,
                                                  int M, int K, int N,
                                                  size_t aBrStride, size_t cBrStride) {
    __shared__ __align__(16) short sA[64 * 64];
    __shared__ __align__(16) short sB[192 * 64];
    int tid = threadIdx.x;
    int wave = tid >> 6, lane = tid & 63;
    int m = lane & 15, q = lane >> 4;
    int row0 = blockIdx.y << 6;
    int col0 = blockIdx.x * 192;
    const short* A = Abase + blockIdx.z * aBrStride;
    unsigned short* Cbfb = Cbf + blockIdx.z * cBrStride;
    int K2 = K * 2;
    floatx4 acc[4][3];
#pragma unroll
    for (int rt = 0; rt < 4; ++rt)
#pragma unroll
        for (int ct = 0; ct < 3; ++ct) acc[rt][ct] = (floatx4){0.f, 0.f, 0.f, 0.f};

    // staging: each wave stages 2 A-chunks (16 rows) + 6 B-chunks (48 rows).
    // chunk = 8 rows x 8 slots x 16B = 1KB; lane l -> row base+(l>>3), slot l&7.
    // content must be source slot (l&7)^(row&7); row&7 == (l>>3)&7 (bases %8==0).
    int lr = lane >> 3, ls = lane & 7;
    int sp = ls ^ (lr & 7);                                   // source slot
    int koff = (sp < 4) ? (sp << 3) : (K + ((sp - 4) << 3));  // shorts
    const short* gA0 = A + (size_t)(row0 + wave * 16 + lr) * K2 + koff;
    const short* gA1 = gA0 + (size_t)8 * K2;
    short* lA0 = &sA[wave * 16 * 64];
    short* lA1 = lA0 + 8 * 64;
    const short* gB[6];
    short* lB[6];
#pragma unroll
    for (int p = 0; p < 6; ++p) {
        int rb = wave * 48 + p * 8;
        gB[p] = Bt + (size_t)(col0 + rb + lr) * K2 + koff;
        lB[p] = &sB[rb * 64];
    }
    int sw_hi = (q ^ (m & 7)) << 3;
    int sw_lo = ((4 + q) ^ (m & 7)) << 3;

    for (int k0 = 0; k0 < K; k0 += 32) {
        gll16(gA0 + k0, lA0);
        gll16(gA1 + k0, lA1);
#pragma unroll
        for (int p = 0; p < 6; ++p)
            gll16(gB[p] + k0, lB[p]);
        __syncthreads();                 // drains vmcnt -> LDS ready
        short8 a_hi[4], a_lo[4];
#pragma unroll
        for (int rt = 0; rt < 4; ++rt) {
            int row = rt * 16 + m;
            a_hi[rt] = *(const short8*)&sA[(row << 6) + sw_hi];
            a_lo[rt] = *(const short8*)&sA[(row << 6) + sw_lo];
        }
#pragma unroll
        for (int ct = 0; ct < 3; ++ct) {
            int bn = wave * 48 + ct * 16 + m;
            short8 b_hi = *(const short8*)&sB[(bn << 6) + sw_hi];
            short8 b_lo = *(const short8*)&sB[(bn << 6) + sw_lo];
#pragma unroll
            for (int rt = 0; rt < 4; ++rt) {
                acc[rt][ct] = __builtin_amdgcn_mfma_f32_16x16x32_bf16(a_hi[rt], b_hi, acc[rt][ct], 0, 0, 0);
                acc[rt][ct] = __builtin_amdgcn_mfma_f32_16x16x32_bf16(a_lo[rt], b_hi, acc[rt][ct], 0, 0, 0);
                acc[rt][ct] = __builtin_amdgcn_mfma_f32_16x16x32_bf16(a_hi[rt], b_lo, acc[rt][ct], 0, 0, 0);
            }
        }
        __syncthreads();                 // reads done before next writes land
    }
#pragma unroll
    for (int rt = 0; rt < 4; ++rt)
#pragma unroll
        for (int ct = 0; ct < 3; ++ct)
#pragma unroll
            for (int r = 0; r < 4; ++r) {
                size_t idx = (size_t)(row0 + rt * 16 + q * 4 + r) * N + col0 + wave * 48 + ct * 16 + m;
                Cbfb[idx] = (unsigned short)f2bf(acc[rt][ct][r]);
            }
    (void)M;
}

// ---------------- GAT pieces (branch-fused; h in bf16) ----------------
__global__ void gat_elr(const unsigned short* __restrict__ h, const float* __restrict__ al,
                        const float* __restrict__ ar, float* __restrict__ el,
                        float* __restrict__ er, int N, int H, int D,
                        size_t hBr, size_t eBr) {
    int wid = (blockIdx.x * blockDim.x + threadIdx.x) >> 6;
    int lane = threadIdx.x & 63;
    if (wid >= 2 * N * H) return;
    int br = wid / (N * H);
    int loc = wid - br * N * H;
    int n = loc / H, hh = loc - n * H;
    const unsigned short* hp = h + br * hBr + ((size_t)n * H + hh) * D;
    const float* alp = al + (size_t)hh * D;
    const float* arp = ar + (size_t)hh * D;
    float sl = 0.f, sr = 0.f;
    for (int d = lane; d < D; d += 64) {
        float v = us2f(hp[d]);
        sl += v * alp[d];
        sr += v * arp[d];
    }
    for (int off = 32; off > 0; off >>= 1) {
        sl += __shfl_down(sl, off, 64);
        sr += __shfl_down(sr, off, 64);
    }
    if (lane == 0) { el[br * eBr + loc] = sl; er[br * eBr + loc] = sr; }
}

__device__ __forceinline__ float lrelu(float v) {
    return (v > 0.f) ? v : NEG_SLOPE * v;
}

// ---------------- per-node softmax -> per-edge records {src, a0,a1,a2} ------
__global__ __launch_bounds__(128) void gat_alpha(
        const float* __restrict__ el_all, const float* __restrict__ er_all,
        const int* __restrict__ src0, const int* __restrict__ src1,
        const int* __restrict__ rs_all, const int* __restrict__ eidx_all,
        float4* __restrict__ rec_all, int N, int H, int E, size_t eBr) {
    int n = blockIdx.x * 2 + (threadIdx.x >> 6);
    int br = blockIdx.y;
    if (n >= N) return;
    const int* src = br ? src1 : src0;
    const int* rs = rs_all + br * (N + 1);
    const int* eidx = eidx_all + br * E;
    const float* el = el_all + br * eBr;
    const float* er = er_all + br * eBr;
    float4* rec = rec_all + (size_t)br * E;
    int lane = threadIdx.x & 63;
    int s0 = rs[n], s1 = rs[n + 1];
    int deg = s1 - s0;
    if (deg <= 0) return;
    float ern0 = er[n * H + 0];
    float ern1 = (H > 1) ? er[n * H + 1] : 0.f;
    float ern2 = (H > 2) ? er[n * H + 2] : 0.f;
    if (deg <= 64) {
        int s = 0;
        float v0 = -INFINITY, v1 = -INFINITY, v2 = -INFINITY;
        if (lane < deg) {
            int e = eidx[s0 + lane];
            s = src[e];
            v0 = lrelu(el[s * H + 0] + ern0);
            if (H > 1) {
                v1 = lrelu(el[s * H + 1] + ern1);
                v2 = lrelu(el[s * H + 2] + ern2);
            }
        }
        float m0 = v0, m1 = v1, m2 = v2;
#pragma unroll
        for (int off = 32; off > 0; off >>= 1) {
            m0 = fmaxf(m0, __shfl_xor(m0, off, 64));
            m1 = fmaxf(m1, __shfl_xor(m1, off, 64));
            m2 = fmaxf(m2, __shfl_xor(m2, off, 64));
        }
        float ex0 = (lane < deg) ? expf(v0 - m0) : 0.f;
        float ex1 = (lane < deg && H > 1) ? expf(v1 - m1) : 0.f;
        float ex2 = (lane < deg && H > 2) ? expf(v2 - m2) : 0.f;
        float d0 = ex0, d1 = ex1, d2 = ex2;
#pragma unroll
        for (int off = 32; off > 0; off >>= 1) {
            d0 += __shfl_xor(d0, off, 64);
            d1 += __shfl_xor(d1, off, 64);
            d2 += __shfl_xor(d2, off, 64);
        }
        if (lane < deg) {
            float4 r;
            r.x = __int_as_float(s);
            r.y = ex0 / d0;
            r.z = (H > 1) ? ex1 / d1 : 0.f;
            r.w = (H > 2) ? ex2 / d2 : 0.f;
            rec[s0 + lane] = r;
        }
    } else {
        float m0 = -INFINITY, m1 = -INFINITY, m2 = -INFINITY;
        for (int j = s0 + lane; j < s1; j += 64) {
            int e = eidx[j], s = src[e];
            m0 = fmaxf(m0, lrelu(el[s * H + 0] + ern0));
            if (H > 1) {
                m1 = fmaxf(m1, lrelu(el[s * H + 1] + ern1));
                m2 = fmaxf(m2, lrelu(el[s * H + 2] + ern2));
            }
        }
#pragma unroll
        for (int off = 32; off > 0; off >>= 1) {
            m0 = fmaxf(m0, __shfl_xor(m0, off, 64));
            m1 = fmaxf(m1, __shfl_xor(m1, off, 64));
            m2 = fmaxf(m2, __shfl_xor(m2, off, 64));
        }
        float d0 = 0.f, d1 = 0.f, d2 = 0.f;
        for (int j = s0 + lane; j < s1; j += 64) {
            int e = eidx[j], s = src[e];
            d0 += expf(lrelu(el[s * H + 0] + ern0) - m0);
            if (H > 1) {
                d1 += expf(lrelu(el[s * H + 1] + ern1) - m1);
                d2 += expf(lrelu(el[s * H + 2] + ern2) - m2);
            }
        }
#pragma unroll
        for (int off = 32; off > 0; off >>= 1) {
            d0 += __shfl_xor(d0, off, 64);
            d1 += __shfl_xor(d1, off, 64);
            d2 += __shfl_xor(d2, off, 64);
        }
        float i0 = 1.f / d0;
        float i1 = (H > 1) ? 1.f / d1 : 0.f;
        float i2 = (H > 2) ? 1.f / d2 : 0.f;
        for (int j = s0 + lane; j < s1; j += 64) {
            int e = eidx[j], s = src[e];
            float4 r;
            r.x = __int_as_float(s);
            r.y = expf(lrelu(el[s * H + 0] + ern0) - m0) * i0;
            r.z = (H > 1) ? expf(lrelu(el[s * H + 1] + ern1) - m1) * i1 : 0.f;
            r.w = (H > 2) ? expf(lrelu(el[s * H + 2] + ern2) - m2) * i2 : 0.f;
            rec[j] = r;
        }
    }
}

// ---------------- full-row aggregation from precomputed records -------------
// Flattened 1D grid with branch->XCD-half pinning: block w -> xcd = w%8
// (empirical); br = (w%8)>=4, node = (w>>3)*4 + (w%8)&3. Halves the per-XCD
// gather working set (L1 layer becomes fully L2-resident) while keeping all
// CUs and all lanes active (unlike r2's combo pinning).
__global__ __launch_bounds__(192) void gat_agg(
        const unsigned short* __restrict__ hb_all, const float4* __restrict__ rec_all,
        const int* __restrict__ rs_all, float4* __restrict__ out4_all,
        short* __restrict__ osplit_all,
        int N, int H, int D, int E, size_t hBr, size_t o4Br, size_t osBr, int splitOut) {
    int w = blockIdx.x;
    int rr = w & 7;
    int br = rr >> 2;
    int n = ((w >> 3) << 2) + (rr & 3);
    if (n >= N) return;
    int HD = H * D;
    int HD4 = HD >> 2;
    int tid = threadIdx.x;
    if (tid >= HD4) return;
    int hh = (tid << 2) / D;
    const unsigned short* hb = hb_all + br * hBr;
    const float4* rec = rec_all + (size_t)br * E;
    const int* rs = rs_all + br * (N + 1);
    int s0 = rs[n], s1 = rs[n + 1];
    int ch = tid << 2;
    float4 a0 = {0.f, 0.f, 0.f, 0.f};
    float4 a1 = {0.f, 0.f, 0.f, 0.f};
    float4 a2 = {0.f, 0.f, 0.f, 0.f};
    float4 a3 = {0.f, 0.f, 0.f, 0.f};
    int i = s0;
    for (; i + 3 < s1; i += 4) {
        float4 r0 = rec[i];
        float4 r1 = rec[i + 1];
        float4 r2 = rec[i + 2];
        float4 r3 = rec[i + 3];
        int sA = __float_as_int(r0.x);
        int sB = __float_as_int(r1.x);
        int sC = __float_as_int(r2.x);
        int sD = __float_as_int(r3.x);
        ushort4 h0 = *(const ushort4*)&hb[(size_t)sA * HD + ch];
        ushort4 h1 = *(const ushort4*)&hb[(size_t)sB * HD + ch];
        ushort4 h2 = *(const ushort4*)&hb[(size_t)sC * HD + ch];
        ushort4 h3 = *(const ushort4*)&hb[(size_t)sD * HD + ch];
        float w0 = (hh == 0) ? r0.y : ((hh == 1) ? r0.z : r0.w);
        float w1 = (hh == 0) ? r1.y : ((hh == 1) ? r1.z : r1.w);
        float w2 = (hh == 0) ? r2.y : ((hh == 1) ? r2.z : r2.w);
        float w3 = (hh == 0) ? r3.y : ((hh == 1) ? r3.z : r3.w);
        a0.x += w0 * us2f(h0.x); a0.y += w0 * us2f(h0.y);
        a0.z += w0 * us2f(h0.z); a0.w += w0 * us2f(h0.w);
        a1.x += w1 * us2f(h1.x); a1.y += w1 * us2f(h1.y);
        a1.z += w1 * us2f(h1.z); a1.w += w1 * us2f(h1.w);
        a2.x += w2 * us2f(h2.x); a2.y += w2 * us2f(h2.y);
        a2.z += w2 * us2f(h2.z); a2.w += w2 * us2f(h2.w);
        a3.x += w3 * us2f(h3.x); a3.y += w3 * us2f(h3.y);
        a3.z += w3 * us2f(h3.z); a3.w += w3 * us2f(h3.w);
    }
    for (; i < s1; ++i) {
        float4 r0 = rec[i];
        int sA = __float_as_int(r0.x);
        ushort4 h0 = *(const ushort4*)&hb[(size_t)sA * HD + ch];
        float w0 = (hh == 0) ? r0.y : ((hh == 1) ? r0.z : r0.w);
        a0.x += w0 * us2f(h0.x); a0.y += w0 * us2f(h0.y);
        a0.z += w0 * us2f(h0.z); a0.w += w0 * us2f(h0.w);
    }
    float4 o;
    o.x = fmaxf(a0.x + a1.x + a2.x + a3.x, 0.f);
    o.y = fmaxf(a0.y + a1.y + a2.y + a3.y, 0.f);
    o.z = fmaxf(a0.z + a1.z + a2.z + a3.z, 0.f);
    o.w = fmaxf(a0.w + a1.w + a2.w + a3.w, 0.f);
    if (splitOut) {
        short* os = osplit_all + br * osBr;
        int HD2 = HD << 1;
        short4v hi, lo;
        hi[0] = f2bf(o.x); lo[0] = f2bf(o.x - bf2f(hi[0]));
        hi[1] = f2bf(o.y); lo[1] = f2bf(o.y - bf2f(hi[1]));
        hi[2] = f2bf(o.z); lo[2] = f2bf(o.z - bf2f(hi[2]));
        hi[3] = f2bf(o.w); lo[3] = f2bf(o.w - bf2f(hi[3]));
        *(short4v*)&os[(size_t)n * HD2 + ch] = hi;
        *(short4v*)&os[(size_t)n * HD2 + HD + ch] = lo;
    } else {
        out4_all[br * o4Br + (size_t)n * HD4 + tid] = o;
    }
}

// Graph max-readout (post-ReLU >=0) via int-bitcast atomicMax. grid.y = branch.
__global__ void seg_max_atomic(const float* __restrict__ g_all, const int* __restrict__ nid,
                               int* __restrict__ out_all, int N, int C,
                               size_t gBr, size_t oBr) {
    int br = blockIdx.y;
    const float* g = g_all + br * gBr;
    int* out = out_all + br * oBr;
    int n0 = blockIdx.x << 5;
    int n1 = n0 + 32; if (n1 > N) n1 = N;
    if (n0 >= N) return;
    for (int c = threadIdx.x; c < C; c += blockDim.x) {
        int cur = nid[n0];
        float m = 0.f;
        for (int n = n0; n < n1; ++n) {
            int gid = nid[n];
            if (gid != cur) {
                atomicMax(&out[cur * C + c], __float_as_int(m));
                cur = gid; m = 0.f;
            }
            m = fmaxf(m, g[(size_t)n * C + c]);
        }
        atomicMax(&out[cur * C + c], __float_as_int(m));
    }
}

// ---------------- small dense layers (grid.z = branch; strides may be 0) ----
__global__ void linear_wave(const float* __restrict__ in, const float* __restrict__ W,
                            const float* __restrict__ bias, float* __restrict__ out,
                            int K, int O, int act, size_t inBr, size_t outBr) {
    int o = blockIdx.x * 4 + (threadIdx.x >> 6);
    int b = blockIdx.y;
    int lane = threadIdx.x & 63;
    if (o >= O) return;
    const float* ip = in + blockIdx.z * inBr + (size_t)b * K;
    float acc = 0.f;
    for (int k = lane; k < K; k += 64)
        acc += ip[k] * W[(size_t)k * O + o];
    for (int off = 32; off > 0; off >>= 1)
        acc += __shfl_down(acc, off, 64);
    if (lane == 0) {
        acc += bias[o];
        if (act == 1) acc = fmaxf(acc, 0.f);
        else if (act == 2) acc = 1.f / (1.f + expf(-acc));
        out[blockIdx.z * outBr + (size_t)b * O + o] = acc;
    }
}

// fc1 fused with the branch gate (K = 256 fixed).
__global__ void linear_cat(const float* __restrict__ gvec, const float* __restrict__ sf,
                           const float* __restrict__ w1, const float* __restrict__ W,
                           const float* __restrict__ bias, float* __restrict__ out,
                           int O, int B128) {
    int o = blockIdx.x * 4 + (threadIdx.x >> 6);
    int b = blockIdx.y;
    int lane = threadIdx.x & 63;
    if (o >= 512) return;
    float w = 1.f / (1.f + expf(-w1[0]));
    float acc = 0.f;
    for (int k = lane; k < 256; k += 64) {
        int br = k >> 7, c = k & 127;
        float v = (1.f - w) * gvec[br * B128 + b * 128 + c] + w * sf[br * B128 + b * 128 + c];
        acc += v * W[(size_t)k * 512 + o];
    }
    for (int off = 32; off > 0; off >>= 1)
        acc += __shfl_down(acc, off, 64);
    if (lane == 0)
        out[(size_t)b * 512 + o] = fmaxf(acc + bias[o], 0.f);
    (void)O;
}

// ---------------- conv1d k=3 as MFMA (im2col on the fly) --------------------
__global__ __launch_bounds__(256) void conv_mfma(const float* __restrict__ x,
                                                 const float* __restrict__ x1,
                                                 const short* __restrict__ w2,
                                                 const float* __restrict__ bias,
                                                 float* __restrict__ y,
                                                 int Cin, int Lin, int Lout,
                                                 int mode, int srcLen,
                                                 size_t xBr, size_t yBr) {
    extern __shared__ __align__(16) char smem[];
    float* sx = (float*)smem;                          // Cin x 68 fp32
    short* sB = (short*)(smem + (size_t)Cin * 68 * 4); // 128 x 72 shorts
    int Kp = Cin * 3;
    int K2 = Kp * 2;
    int b = blockIdx.y;
    float* yb = y + blockIdx.z * yBr + (size_t)b * 128 * Lout;
    int l0 = blockIdx.x << 6;
    int tid = threadIdx.x;
    int wave = tid >> 6, lane = tid & 63;
    int m = lane & 15, q = lane >> 4;
    int wrow = (wave & 1) << 5;
    int wcol = (wave >> 1) << 6;
    int loadL = Lin - l0; if (loadL > 66) loadL = 66;
    if (mode == 2) {
        const float* pb = (blockIdx.z ? x1 : x) + (size_t)b * 1200 * 64;
        for (int t = tid; t < loadL * 64; t += 256) {
            int i = t >> 6, c = t & 63;
            sx[c * 68 + i] = pb[(size_t)(l0 + i) * 64 + c];
        }
    } else if (mode == 1) {
        const float* xb = x + blockIdx.z * xBr + (size_t)b * Cin * srcLen;
        for (int t = tid; t < Cin * loadL; t += 256) {
            int c = t / loadL, i = t - c * loadL;
            const float* row = &xb[(size_t)c * srcLen + 3 * (l0 + i)];
            sx[c * 68 + i] = fmaxf(fmaxf(row[0], row[1]), row[2]);
        }
    } else {
        const float* xb = x + blockIdx.z * xBr + (size_t)b * Cin * srcLen;
        for (int t = tid; t < Cin * loadL; t += 256) {
            int c = t / loadL, i = t - c * loadL;
            sx[c * 68 + i] = xb[(size_t)c * srcLen + l0 + i];
        }
    }
    floatx4 acc[2][4];
#pragma unroll
    for (int rt = 0; rt < 2; ++rt)
#pragma unroll
        for (int ct = 0; ct < 4; ++ct) acc[rt][ct] = (floatx4){0.f, 0.f, 0.f, 0.f};

    for (int k0 = 0; k0 < Kp; k0 += 32) {
#pragma unroll
        for (int p = 0; p < 4; ++p) {
            int t = tid + (p << 8);
            int o = t >> 3, slot = t & 7;
            int srcoff = k0 + ((slot & 3) << 3) + ((slot >= 4) ? Kp : 0);
            *(float4*)&sB[o * 72 + (slot << 3)] = *(const float4*)&w2[(size_t)o * K2 + srcoff];
        }
        __syncthreads();
        short8 a_hi[2], a_lo[2];
#pragma unroll
        for (int rt = 0; rt < 2; ++rt) {
            int pos = wrow + rt * 16 + m;
#pragma unroll
            for (int kk = 0; kk < 8; ++kk) {
                int k = k0 + q * 8 + kk;
                int c = k / 3, j = k - c * 3;
                float v = sx[c * 68 + pos + j];
                short hv = f2bf(v);
                a_hi[rt][kk] = hv;
                a_lo[rt][kk] = f2bf(v - bf2f(hv));
            }
        }
#pragma unroll
        for (int ct = 0; ct < 4; ++ct) {
            short8 b_hi = *(const short8*)&sB[(wcol + ct * 16 + m) * 72 + q * 8];
            short8 b_lo = *(const short8*)&sB[(wcol + ct * 16 + m) * 72 + 32 + q * 8];
#pragma unroll
            for (int rt = 0; rt < 2; ++rt) {
                acc[rt][ct] = __builtin_amdgcn_mfma_f32_16x16x32_bf16(a_hi[rt], b_hi, acc[rt][ct], 0, 0, 0);
                acc[rt][ct] = __builtin_amdgcn_mfma_f32_16x16x32_bf16(a_lo[rt], b_hi, acc[rt][ct], 0, 0, 0);
                acc[rt][ct] = __builtin_amdgcn_mfma_f32_16x16x32_bf16(a_hi[rt], b_lo, acc[rt][ct], 0, 0, 0);
            }
        }
        __syncthreads();
    }
#pragma unroll
    for (int ct = 0; ct < 4; ++ct) {
        int o = wcol + ct * 16 + m;
        float bv = bias[o];
#pragma unroll
        for (int rt = 0; rt < 2; ++rt)
#pragma unroll
            for (int r = 0; r < 4; ++r) {
                int pos = wrow + rt * 16 + q * 4 + r;
                if (l0 + pos < Lout)
                    yb[(size_t)o * Lout + l0 + pos] = acc[rt][ct][r] + bv;
            }
    }
}

// fused: global 130-max-pool over y3 + tf linear + ReLU. block per (b, br).
__global__ void pooltf(const float* __restrict__ y3, const float* __restrict__ tf_w,
                       const float* __restrict__ tf_b, float* __restrict__ sf,
                       size_t yBr, size_t sfBr) {
    __shared__ float s_sp[128];
    int b = blockIdx.x, br = blockIdx.y;
    const float* yb = y3 + br * yBr + (size_t)b * 128 * 130;
    int c = threadIdx.x;
    float mx = -INFINITY;
    for (int l = 0; l < 130; ++l) mx = fmaxf(mx, yb[(size_t)c * 130 + l]);
    s_sp[c] = mx;
    __syncthreads();
    int o = threadIdx.x;
    float acc = tf_b[o];
    for (int k = 0; k < 128; ++k) acc += s_sp[k] * tf_w[(size_t)k * 128 + o];
    sf[br * sfBr + (size_t)b * 128 + o] = fmaxf(acc, 0.f);
}

// ---------------- host ----------------
extern "C" void kernel_launch(void* const* d_in, const int* in_sizes, int n_in,
                              void* d_out, int out_size, void* d_ws, size_t ws_size,
                              hipStream_t stream) {
    const float* feat[2] = {(const float*)d_in[0], (const float*)d_in[1]};
    const float* pad[2]  = {(const float*)d_in[2], (const float*)d_in[3]};
    const int* src[2]    = {(const int*)d_in[4], (const int*)d_in[6]};
    const int* dst[2]    = {(const int*)d_in[5], (const int*)d_in[7]};
    const int* nid[2]    = {(const int*)d_in[8], (const int*)d_in[9]};
    const float* Wg[3]   = {(const float*)d_in[11], (const float*)d_in[14], (const float*)d_in[17]};
    const float* al[3]   = {(const float*)d_in[12], (const float*)d_in[15], (const float*)d_in[18]};
    const float* ar[3]   = {(const float*)d_in[13], (const float*)d_in[16], (const float*)d_in[19]};
    const float* fcg_w = (const float*)d_in[20]; const float* fcg_b = (const float*)d_in[21];
    const float* c1w = (const float*)d_in[22];   const float* c1b = (const float*)d_in[23];
    const float* c2w = (const float*)d_in[24];   const float* c2b = (const float*)d_in[25];
    const float* c3w = (const float*)d_in[26];   const float* c3b = (const float*)d_in[27];
    const float* tf_w = (const float*)d_in[28];  const float* tf_b = (const float*)d_in[29];
    const float* w1 = (const float*)d_in[30];
    const float* fc1_w = (const float*)d_in[31]; const float* fc1_b = (const float*)d_in[32];
    const float* fc2_w = (const float*)d_in[33]; const float* fc2_b = (const float*)d_in[34];
    const float* outw = (const float*)d_in[35];  const float* outb = (const float*)d_in[36];
    float* out = (float*)d_out;

    const int N = in_sizes[0] / 64;   // 8000
    const int E = in_sizes[4];        // 160000
    const int B = 16, L = 1200;
    const size_t NS = (size_t)N * 576;

    char* wsb = (char*)d_ws;
    size_t off = 0;
    auto allocB = [&](size_t bytes) -> void* {
        void* p = wsb + off;
        off += (bytes + 255) & ~(size_t)255;
        return p;
    };
    auto alloc = [&](size_t elems) -> void* { return allocB(elems * 4); };

    unsigned short* h_bf = (unsigned short*)allocB(2 * NS * 2);
    float* gA    = (float*)alloc(2 * NS);          // L3 f32 out; also hosts L1 split (shorts)
    float* el    = (float*)alloc(2 * (size_t)N * 3);
    float* er    = (float*)alloc(2 * (size_t)N * 3);
    int* rs      = (int*)alloc(2 * (N + 1));
    int* cnt     = (int*)alloc(2 * N);
    int* eidx    = (int*)alloc(2 * E);
    int* gmax    = (int*)alloc(2 * (size_t)B * 576);
    float* gvec  = (float*)alloc(2 * (size_t)B * 128);
    float* sf    = (float*)alloc(2 * (size_t)B * 128);
    float* f1    = (float*)alloc((size_t)B * 512);
    float* f2    = (float*)alloc((size_t)B * 256);
    float4* rec  = (float4*)allocB((size_t)2 * E * 16);
    short* fsplit = (short*)allocB((size_t)2 * 8000 * 128 * 2);
    short* w2t1  = (short*)allocB((size_t)192 * 2 * 64 * 2);
    short* w2t2  = (short*)allocB((size_t)576 * 2 * 192 * 2);
    short* w2t3  = (short*)allocB((size_t)576 * 2 * 576 * 2);
    short* cw1   = (short*)allocB((size_t)128 * 2 * 192 * 2);
    short* cw2   = (short*)allocB((size_t)128 * 2 * 384 * 2);
    short* cw3   = (short*)allocB((size_t)128 * 2 * 384 * 2);
    // UNION: L2 split (2 x 8000 x 1152 shorts = 36.9 MB) aliases TextCNN scratch
    size_t tcnn_elems = 2 * (size_t)B * 128 * (1198 + 397 + 130);
    size_t uni_elems = 2 * NS > tcnn_elems ? 2 * NS : tcnn_elems;
    float* uni = (float*)alloc(uni_elems);
    float* y1 = uni;
    float* y2 = y1 + 2 * (size_t)B * 128 * 1198;
    float* y3 = y2 + 2 * (size_t)B * 128 * 397;
    short* splitA1 = (short*)gA;     // L1 out (2 x 8000 x 384 shorts), consumed by GEMM2
    short* splitA2 = (short*)uni;    // L2 out (2 x 8000 x 1152 shorts), consumed by GEMM3
    (void)ws_size; (void)n_in; (void)out_size; (void)L;

    prep_weights<<<6257, 256, 0, stream>>>(Wg[0], Wg[1], Wg[2], c1w, c2w, c3w,
                                           w2t1, w2t2, w2t3, cw1, cw2, cw3,
                                           feat[0], feat[1], fsplit);
    short* w2t[3] = {w2t1, w2t2, w2t3};

    // --- CSR for both branches (scan zeroes cnt for reuse as fill) ---
    zero_i32<<<(2 * N + 255) / 256, 256, 0, stream>>>(cnt, 2 * N);
    count_edges2<<<(2 * E + 255) / 256, 256, 0, stream>>>(dst[0], dst[1], cnt, N, E);
    scan_block<<<2, 1024, 0, stream>>>(cnt, rs, N);
    scatter_edges2<<<(2 * E + 255) / 256, 256, 0, stream>>>(dst[0], dst[1], rs, cnt, eidx, N, E);

    // --- 3 GAT layers, both branches per dispatch ---
    const int dims[3][3] = {{64, 3, 64}, {192, 3, 192}, {576, 1, 576}};
    const short* aIn = fsplit;
    size_t aBr = (size_t)N * 128;
    int aggBlocks = ((N + 3) / 4) * 8;
    for (int ly = 0; ly < 3; ++ly) {
        int K = dims[ly][0], H = dims[ly][1], D = dims[ly][2];
        int HD = H * D;
        gemm_split<<<dim3(HD / 192, N / 64, 2), 256, 0, stream>>>(aIn, w2t[ly], h_bf,
                                                                  N, K, HD, aBr, NS);
        int waves2 = 2 * N * H;
        gat_elr<<<((size_t)waves2 * 64 + 255) / 256, 256, 0, stream>>>(h_bf, al[ly], ar[ly], el, er,
                                                                       N, H, D, NS, (size_t)N * 3);
        gat_alpha<<<dim3((N + 1) / 2, 2), 128, 0, stream>>>(el, er, src[0], src[1], rs, eidx,
                                                            rec, N, H, E, (size_t)N * 3);
        int aggThreads = (((HD >> 2) + 63) / 64) * 64;
        int splitOut = (ly < 2) ? 1 : 0;
        short* osp = (ly == 0) ? splitA1 : splitA2;
        gat_agg<<<aggBlocks, aggThreads, 0, stream>>>(
            h_bf, rec, rs, (float4*)gA, osp,
            N, H, D, E, NS, NS / 4, (size_t)N * (size_t)(2 * HD), splitOut);
        aIn = osp;
        aBr = (size_t)N * (size_t)(2 * HD);
    }
    zero_i32<<<(2 * B * 576 + 255) / 256, 256, 0, stream>>>(gmax, 2 * B * 576);
    seg_max_atomic<<<dim3((N + 31) / 32, 2), 256, 0, stream>>>(gA, nid[0], gmax, N, 576,
                                                               NS, (size_t)B * 576);
    linear_wave<<<dim3(32, B, 2), 256, 0, stream>>>((const float*)gmax, fcg_w, fcg_b, gvec,
                                                    576, 128, 1, (size_t)B * 576, (size_t)B * 128);

    // --- TextCNN (MFMA convs; transpose / pools fused into staging) ---
    conv_mfma<<<dim3(19, B, 2), 256, 64 * 68 * 4 + 128 * 72 * 2, stream>>>(
        pad[0], pad[1], cw1, c1b, y1, 64, 1200, 1198, 2, 0,
        0, (size_t)B * 128 * 1198);
    conv_mfma<<<dim3(7, B, 2), 256, 128 * 68 * 4 + 128 * 72 * 2, stream>>>(
        y1, nullptr, cw2, c2b, y2, 128, 399, 397, 1, 1198,
        (size_t)B * 128 * 1198, (size_t)B * 128 * 397);
    conv_mfma<<<dim3(3, B, 2), 256, 128 * 68 * 4 + 128 * 72 * 2, stream>>>(
        y2, nullptr, cw3, c3b, y3, 128, 132, 130, 1, 397,
        (size_t)B * 128 * 397, (size_t)B * 128 * 130);
    pooltf<<<dim3(B, 2), 128, 0, stream>>>(y3, tf_w, tf_b, sf,
                                           (size_t)B * 128 * 130, (size_t)B * 128);

    // --- head MLP (fc1 fused with branch gate) ---
    linear_cat<<<dim3(128, B, 1), 256, 0, stream>>>(gvec, sf, w1, fc1_w, fc1_b, f1, 512, B * 128);
    linear_wave<<<dim3(64, B, 1), 256, 0, stream>>>(f1, fc2_w, fc2_b, f2, 512, 256, 1, 0, 0);
    linear_wave<<<dim3(1, B, 1), 256, 0, stream>>>(f2, outw, outb, out, 256, 1, 2, 0, 0);
}